// Round 5
// baseline (4077.377 us; speedup 1.0000x reference)
//
#include <hip/hip_runtime.h>
#include <hip/hip_fp16.h>
#include <math.h>

#define NATOMS 40000
#define NEDGE  400000
#define NCRYS  400

// ---- workspace layout (float-slot offsets); high-water 18,496,384 floats = 74.0 MB ----
#define O_W    0                        // weights[40000] fp32
#define O_X    40960                    // x[40000*128] fp16 (2,560,000 slots)
#define O_XCAT 2600960                  // xcat[40000*512] fp16 (10,240,000 slots)
#define O_SUM  12840960                 // summed[40000*128] fp32
#define O_STAT 17960960                 // stats block [4096]
#define O_CRYS 17965056                 // crys[400*128] fp32
#define O_PTR  18016256                 // CSR row ptr [40001] int
#define O_DEG  18056320                 // degree/cursor [40000] int
#define O_EORD 18096384                 // edge order [400000] int
// stat indices (within O_STAT)
#define S1SUM 0      // [0,256)
#define S1SQ  256    // [256,512)
#define S2SUM 512    // [512,640)
#define S2SQ  640    // [640,768)
#define SWE   768
// per-conv zero region = [0, 772)
#define SC1   1024   // [1024,1280)
#define SH1   1280   // [1280,1536)
#define SC2   1536   // [1536,1664)
#define SH2   1664   // [1664,1792)
#define SWA   1792
#define SWC   1800   // [1800,2200)
// startup zero region = [1792, 4096) + crys

__device__ __forceinline__ float sp_f(float v) {
    return fmaxf(v, 0.f) + log1pf(expf(-fabsf(v)));
}
__device__ __forceinline__ float sig_f(float v) {
    return 1.f / (1.f + expf(-v));
}
__device__ __forceinline__ unsigned pack_h2(float a, float b) {
    __half2 h = __floats2half2_rn(a, b);
    return *reinterpret_cast<unsigned*>(&h);
}
__device__ __forceinline__ void ld4h(const __half* p, float* o) {
    int2 r = *reinterpret_cast<const int2*>(p);
    __half2 h0 = *reinterpret_cast<const __half2*>(&r.x);
    __half2 h1 = *reinterpret_cast<const __half2*>(&r.y);
    float2 f0 = __half22float2(h0), f1 = __half22float2(h1);
    o[0] = f0.x; o[1] = f0.y; o[2] = f1.x; o[3] = f1.y;
}
__device__ __forceinline__ void st4h(__half* p, const float* v) {
    uint2 pk;
    pk.x = pack_h2(v[0], v[1]); pk.y = pack_h2(v[2], v[3]);
    *reinterpret_cast<uint2*>(p) = pk;
}

// ---- embedding: weights[a]=af[a][0]; x = af[:,1:] @ embW + embB (x stored fp16) ----
__global__ __launch_bounds__(128) void k_embed(const float* __restrict__ af,
        const float* __restrict__ embW, const float* __restrict__ embB,
        float* __restrict__ ws) {
    __shared__ float at[93 * 36];   // transposed: at[k*36+m], 32 atoms/block
    int a0 = blockIdx.x * 32;
    int tid = threadIdx.x;
    for (int p = tid; p < 32 * 93; p += 128) {
        int m = p / 93, k = p - m * 93;
        at[k * 36 + m] = af[(size_t)a0 * 93 + p];
    }
    __syncthreads();
    int cq = tid & 31;   // cols cq*4..+3
    int ag = tid >> 5;   // atoms ag*8..+7
    float acc[8][4];
    float4 bb = *reinterpret_cast<const float4*>(&embB[cq * 4]);
    #pragma unroll
    for (int m = 0; m < 8; m++) { acc[m][0] = bb.x; acc[m][1] = bb.y; acc[m][2] = bb.z; acc[m][3] = bb.w; }
    for (int k = 0; k < 92; k++) {
        float4 wv = *reinterpret_cast<const float4*>(&embW[k * 128 + cq * 4]);
        const float* arow = &at[(k + 1) * 36 + ag * 8];
        #pragma unroll
        for (int m = 0; m < 8; m++) {
            float av = arow[m];
            acc[m][0] += av * wv.x; acc[m][1] += av * wv.y;
            acc[m][2] += av * wv.z; acc[m][3] += av * wv.w;
        }
    }
    __half* xh = reinterpret_cast<__half*>(ws + O_X);
    #pragma unroll
    for (int m = 0; m < 8; m++) {
        int a = a0 + ag * 8 + m;
        st4h(&xh[(size_t)a * 128 + cq * 4], acc[m]);
    }
    if (tid < 32) ws[O_W + a0 + tid] = at[0 * 36 + tid];
    if (tid == 0) {
        float s = 0.f;
        for (int m = 0; m < 32; m++) s += at[0 * 36 + m];
        atomicAdd(&ws[O_STAT + SWA], s);
    }
}

// ---- CSR build: hist -> scan -> scatter ----
__global__ void k_hist(const int* __restrict__ eidx, float* __restrict__ ws) {
    int e = blockIdx.x * 256 + threadIdx.x;
    int* deg = (int*)(ws + O_DEG);
    if (e < NEDGE) atomicAdd(&deg[eidx[(size_t)e * 2]], 1);
}

__global__ __launch_bounds__(1024) void k_scan(float* __restrict__ ws) {
    const int* deg = (const int*)(ws + O_DEG);
    int* ptr = (int*)(ws + O_PTR);
    __shared__ int buf[1024];
    __shared__ int carry;
    int t = threadIdx.x;
    if (t == 0) carry = 0;
    __syncthreads();
    for (int c = 0; c < 40; c++) {
        int i = c * 1024 + t;
        int v = (i < NATOMS) ? deg[i] : 0;
        buf[t] = v;
        __syncthreads();
        for (int off = 1; off < 1024; off <<= 1) {
            int u = (t >= off) ? buf[t - off] : 0;
            __syncthreads();
            buf[t] += u;
            __syncthreads();
        }
        int inc = buf[t];
        if (i < NATOMS) ptr[i] = carry + inc - v;   // exclusive scan
        __syncthreads();
        if (t == 1023) carry += inc;
        __syncthreads();
    }
    if (t == 0) ptr[NATOMS] = carry;
}

__global__ void k_scatter(const int* __restrict__ eidx, float* __restrict__ ws) {
    int e = blockIdx.x * 256 + threadIdx.x;
    if (e >= NEDGE) return;
    const int* ptr = (const int*)(ws + O_PTR);
    int* cur = (int*)(ws + O_DEG);            // re-zeroed before this kernel
    int* eord = (int*)(ws + O_EORD);
    int i0 = eidx[(size_t)e * 2];
    int pos = ptr[i0] + atomicAdd(&cur[i0], 1);
    eord[pos] = e;
}

// ---- xcat = x @ [Wa | Wb]  -> fp16 (per conv) ----
__global__ __launch_bounds__(256) void k_xcat(const float* __restrict__ Wi,
        float* __restrict__ ws) {
    __shared__ float xt[128 * 36];   // xt[k*36+m], 32 atoms
    const __half* xh = reinterpret_cast<const __half*>(ws + O_X);
    __half* xcp = reinterpret_cast<__half*>(ws + O_XCAT);
    int a0 = blockIdx.x * 32;
    int tid = threadIdx.x;
    for (int p = tid * 4; p < 32 * 128; p += 1024) {
        float v4[4];
        ld4h(&xh[(size_t)a0 * 128 + p], v4);
        int m = p >> 7, k = p & 127;
        xt[k * 36 + m] = v4[0]; xt[(k + 1) * 36 + m] = v4[1];
        xt[(k + 2) * 36 + m] = v4[2]; xt[(k + 3) * 36 + m] = v4[3];
    }
    __syncthreads();
    int cq = tid & 63, ag = tid >> 6;
    int hb = cq >> 5;            // 0: xa (W rows 0..127), 1: xb (W rows 128..255)
    int c0 = (cq & 31) * 8;      // col within half
    const float* Wp = Wi + (size_t)hb * 128 * 256;
    float acc[8][8];
    #pragma unroll
    for (int m = 0; m < 8; m++)
        #pragma unroll
        for (int j = 0; j < 8; j++) acc[m][j] = 0.f;
    for (int k = 0; k < 128; k++) {
        float4 w0 = *reinterpret_cast<const float4*>(&Wp[k * 256 + c0]);
        float4 w1 = *reinterpret_cast<const float4*>(&Wp[k * 256 + c0 + 4]);
        const float* xr = &xt[k * 36 + ag * 8];
        #pragma unroll
        for (int m = 0; m < 8; m++) {
            float xv = xr[m];
            acc[m][0] += xv * w0.x; acc[m][1] += xv * w0.y;
            acc[m][2] += xv * w0.z; acc[m][3] += xv * w0.w;
            acc[m][4] += xv * w1.x; acc[m][5] += xv * w1.y;
            acc[m][6] += xv * w1.z; acc[m][7] += xv * w1.w;
        }
    }
    #pragma unroll
    for (int m = 0; m < 8; m++) {
        int a = a0 + ag * 8 + m;
        uint4 pk;
        pk.x = pack_h2(acc[m][0], acc[m][1]);
        pk.y = pack_h2(acc[m][2], acc[m][3]);
        pk.z = pack_h2(acc[m][4], acc[m][5]);
        pk.w = pack_h2(acc[m][6], acc[m][7]);
        *reinterpret_cast<uint4*>(&xcp[(size_t)a * 512 + hb * 256 + c0]) = pk;
    }
}

// ---- BN1 stats pass: g = e@We + xa[i0] + xb[i1]; weighted sums (no store of g) ----
__global__ __launch_bounds__(256) void k_edge0(const float* __restrict__ nbr,
        const int* __restrict__ eidx, const float* __restrict__ Wi,
        float* __restrict__ ws) {
    __shared__ float lds[4352];      // et[41*64]=2624; reused as red[4096]
    __shared__ float wl[64];
    __shared__ int i0l[64], i1l[64];
    float* st = ws + O_STAT;
    const __half* xc = reinterpret_cast<const __half*>(ws + O_XCAT);
    int tid = threadIdx.x;
    int cq = tid & 31, eq = tid >> 5;

    float sF[4] = {0,0,0,0}, sC[4] = {0,0,0,0}, qF[4] = {0,0,0,0}, qC[4] = {0,0,0,0};
    float swe_acc = 0.f;
    for (int g = 0; g < 2; ++g) {
        int e0 = (blockIdx.x + g * 3125) * 64;
        __syncthreads();   // protect lds reuse from previous tile
        for (int q = tid; q < 672; q += 256) {
            float4 v = *reinterpret_cast<const float4*>(&nbr[(size_t)e0 * 42 + q * 4]);
            float va[4] = {v.x, v.y, v.z, v.w};
            #pragma unroll
            for (int j = 0; j < 4; j++) {
                int p = q * 4 + j;
                int m = p / 42;
                int k = p - m * 42;
                if (k < 41) lds[k * 64 + m] = va[j]; else wl[m] = va[j];
            }
        }
        if (tid < 64) {
            i0l[tid] = eidx[(size_t)(e0 + tid) * 2];
            i1l[tid] = eidx[(size_t)(e0 + tid) * 2 + 1];
        }
        __syncthreads();

        float ef[8][4], ec[8][4];
        #pragma unroll
        for (int m = 0; m < 8; m++)
            #pragma unroll
            for (int j = 0; j < 4; j++) { ef[m][j] = 0.f; ec[m][j] = 0.f; }
        for (int k = 0; k < 41; k++) {
            float4 wf = *reinterpret_cast<const float4*>(&Wi[(256 + k) * 256 + cq * 4]);
            float4 wc = *reinterpret_cast<const float4*>(&Wi[(256 + k) * 256 + 128 + cq * 4]);
            const float* ev = &lds[k * 64 + eq * 8];
            #pragma unroll
            for (int m = 0; m < 8; m++) {
                float e = ev[m];
                ef[m][0] += e * wf.x; ef[m][1] += e * wf.y;
                ef[m][2] += e * wf.z; ef[m][3] += e * wf.w;
                ec[m][0] += e * wc.x; ec[m][1] += e * wc.y;
                ec[m][2] += e * wc.z; ec[m][3] += e * wc.w;
            }
        }
        #pragma unroll
        for (int m = 0; m < 8; m++) {
            int em = eq * 8 + m;
            int i0 = i0l[em], i1 = i1l[em];
            float xaf[4], xac[4], xbf[4], xbc[4];
            ld4h(&xc[(size_t)i0 * 512 + cq * 4], xaf);
            ld4h(&xc[(size_t)i0 * 512 + 128 + cq * 4], xac);
            ld4h(&xc[(size_t)i1 * 512 + 256 + cq * 4], xbf);
            ld4h(&xc[(size_t)i1 * 512 + 384 + cq * 4], xbc);
            float w = wl[em];
            #pragma unroll
            for (int j = 0; j < 4; j++) {
                float gf = ef[m][j] + xaf[j] + xbf[j];
                float gc = ec[m][j] + xac[j] + xbc[j];
                float tf = w * gf, tc = w * gc;
                sF[j] += tf; qF[j] += tf * gf;
                sC[j] += tc; qC[j] += tc * gc;
            }
        }
        if (tid == 0) {
            float s = 0.f;
            for (int m = 0; m < 64; m++) s += wl[m];
            swe_acc += s;
        }
    }
    __syncthreads();
    #pragma unroll
    for (int j = 0; j < 4; j++) {
        lds[eq * 512 + cq * 4 + j]       = sF[j];
        lds[eq * 512 + 128 + cq * 4 + j] = sC[j];
        lds[eq * 512 + 256 + cq * 4 + j] = qF[j];
        lds[eq * 512 + 384 + cq * 4 + j] = qC[j];
    }
    __syncthreads();
    for (int pos = tid; pos < 512; pos += 256) {
        float v = 0.f;
        #pragma unroll
        for (int q8 = 0; q8 < 8; q8++) v += lds[q8 * 512 + pos];
        atomicAdd(&st[pos], v);
    }
    if (tid == 0) atomicAdd(&st[SWE], swe_acc);
}

__global__ void k_fin1(const float* __restrict__ bn1g, const float* __restrict__ bn1b,
        float* __restrict__ ws) {
    float* st = ws + O_STAT;
    int c = threadIdx.x;  // 256
    float sw = st[SWE];
    float mean = st[S1SUM + c] / sw;
    float var = st[S1SQ + c] / sw - mean * mean;
    float sc = bn1g[c] / sqrtf(var + 1e-5f);
    st[SC1 + c] = sc;
    st[SH1 + c] = bn1b[c] - mean * sc;
}

// ---- per-atom apply pass: block = atom; recompute g for its CSR edges; no scatter atomics ----
__global__ __launch_bounds__(256) void k_msg_atom(const float* __restrict__ nbr,
        const int* __restrict__ eidx, const float* __restrict__ Wi,
        float* __restrict__ ws) {
    __shared__ float elds[8 * 41];
    __shared__ int i1l[8];
    __shared__ float red[1024];
    int a = blockIdx.x;
    int tid = threadIdx.x;
    int cq = tid & 31, eq = tid >> 5;
    const int* ptr = (const int*)(ws + O_PTR);
    const int* eord = (const int*)(ws + O_EORD);
    const __half* xc = reinterpret_cast<const __half*>(ws + O_XCAT);
    const float* st = ws + O_STAT;
    float* summed = ws + O_SUM;

    int p0 = ptr[a], p1 = ptr[a + 1];
    float scf[4], shf[4], scc[4], shc[4];
    #pragma unroll
    for (int j = 0; j < 4; j++) {
        scf[j] = st[SC1 + cq * 4 + j];
        shf[j] = st[SH1 + cq * 4 + j];
        scc[j] = st[SC1 + 128 + cq * 4 + j];
        shc[j] = st[SH1 + 128 + cq * 4 + j];
    }
    float xaf[4], xac[4];
    ld4h(&xc[(size_t)a * 512 + cq * 4], xaf);
    ld4h(&xc[(size_t)a * 512 + 128 + cq * 4], xac);

    float macc[4] = {0, 0, 0, 0};
    for (int base = p0; base < p1; base += 8) {
        __syncthreads();   // protect elds reuse
        if (base + eq < p1) {
            int e = eord[base + eq];
            if (cq == 0) i1l[eq] = eidx[(size_t)e * 2 + 1];
            elds[eq * 41 + cq] = nbr[(size_t)e * 42 + cq];
            if (cq + 32 < 41) elds[eq * 41 + 32 + cq] = nbr[(size_t)e * 42 + 32 + cq];
        }
        __syncthreads();
        if (base + eq < p1) {
            float ef[4] = {0,0,0,0}, ec[4] = {0,0,0,0};
            const float* ev = &elds[eq * 41];
            for (int k = 0; k < 41; k++) {
                float4 wf = *reinterpret_cast<const float4*>(&Wi[(256 + k) * 256 + cq * 4]);
                float4 wc = *reinterpret_cast<const float4*>(&Wi[(256 + k) * 256 + 128 + cq * 4]);
                float e = ev[k];
                ef[0] += e * wf.x; ef[1] += e * wf.y; ef[2] += e * wf.z; ef[3] += e * wf.w;
                ec[0] += e * wc.x; ec[1] += e * wc.y; ec[2] += e * wc.z; ec[3] += e * wc.w;
            }
            int i1 = i1l[eq];
            float xbf[4], xbc[4];
            ld4h(&xc[(size_t)i1 * 512 + 256 + cq * 4], xbf);
            ld4h(&xc[(size_t)i1 * 512 + 384 + cq * 4], xbc);
            #pragma unroll
            for (int j = 0; j < 4; j++) {
                float gf = ef[j] + xaf[j] + xbf[j];
                float gc = ec[j] + xac[j] + xbc[j];
                float fn = gf * scf[j] + shf[j];
                float cn = gc * scc[j] + shc[j];
                macc[j] += sig_f(fn) * sp_f(cn);
            }
        }
    }
    __syncthreads();
    #pragma unroll
    for (int j = 0; j < 4; j++) red[eq * 128 + cq * 4 + j] = macc[j];
    __syncthreads();
    if (tid < 128) {
        float v = 0.f;
        #pragma unroll
        for (int q8 = 0; q8 < 8; q8++) v += red[q8 * 128 + tid];
        summed[(size_t)a * 128 + tid] = v;
    }
}

__global__ __launch_bounds__(256) void k_stats2(float* __restrict__ ws) {
    const float* sm = ws + O_SUM;
    const float* w = ws + O_W;
    float* st = ws + O_STAT;
    int tid = threadIdx.x;
    int c = tid & 127, r = tid >> 7;
    float s = 0.f, q = 0.f;
    for (int a = blockIdx.x * 2 + r; a < NATOMS; a += 512) {
        float wa = w[a];
        float v = sm[(size_t)a * 128 + c];
        s += wa * v; q += wa * v * v;
    }
    __shared__ float rs[256], rq[256];
    rs[tid] = s; rq[tid] = q;
    __syncthreads();
    if (r == 0) {
        atomicAdd(&st[S2SUM + c], s + rs[tid + 128]);
        atomicAdd(&st[S2SQ + c], q + rq[tid + 128]);
    }
}

__global__ void k_fin2(const float* __restrict__ bn2g, const float* __restrict__ bn2b,
        float* __restrict__ ws) {
    float* st = ws + O_STAT;
    int c = threadIdx.x;  // 128
    float sw = st[SWA];
    float mean = st[S2SUM + c] / sw;
    float var = st[S2SQ + c] / sw - mean * mean;
    float sc = bn2g[c] / sqrtf(var + 1e-5f);
    st[SC2 + c] = sc;
    st[SH2 + c] = bn2b[c] - mean * sc;
}

__global__ __launch_bounds__(256) void k_updx(float* __restrict__ ws) {
    __half* xh = reinterpret_cast<__half*>(ws + O_X);
    const float* sm = ws + O_SUM;
    const float* st = ws + O_STAT;
    int i = blockIdx.x * 256 + threadIdx.x;   // 4-elem group index, 1,280,000 total
    int c4 = (i & 31) * 4;
    float xv[4];
    ld4h(&xh[(size_t)i * 4], xv);
    float4 sv = *reinterpret_cast<const float4*>(&sm[(size_t)i * 4]);
    float4 sc = *reinterpret_cast<const float4*>(&st[SC2 + c4]);
    float4 sh = *reinterpret_cast<const float4*>(&st[SH2 + c4]);
    float o[4];
    o[0] = sp_f(xv[0] + sv.x * sc.x + sh.x);
    o[1] = sp_f(xv[1] + sv.y * sc.y + sh.y);
    o[2] = sp_f(xv[2] + sv.z * sc.z + sh.z);
    o[3] = sp_f(xv[3] + sv.w * sc.w + sh.w);
    st4h(&xh[(size_t)i * 4], o);
}

__global__ void k_pool1(const int* __restrict__ cidx, float* __restrict__ ws) {
    int a = blockIdx.x * 256 + threadIdx.x;
    if (a < NATOMS) atomicAdd(&ws[O_STAT + SWC + cidx[a]], ws[O_W + a]);
}

__global__ void k_pool2(const int* __restrict__ cidx, float* __restrict__ ws) {
    int i = blockIdx.x * 256 + threadIdx.x;   // 5,120,000
    int a = i >> 7, c = i & 127;
    int s = cidx[a];
    const __half* xh = reinterpret_cast<const __half*>(ws + O_X);
    float coef = ws[O_W + a] / ws[O_STAT + SWC + s];
    atomicAdd(&ws[O_CRYS + (size_t)s * 128 + c], coef * __half2float(xh[(size_t)i]));
}

__global__ __launch_bounds__(256) void k_head(const float* __restrict__ fc1W,
        const float* __restrict__ fc1b, const float* __restrict__ fc2W,
        const float* __restrict__ fc2b, const float* __restrict__ outW,
        const float* __restrict__ outb, const float* __restrict__ ws,
        float* __restrict__ out) {
    __shared__ float spx[128], h1[256], h2[256], rr[4];
    int b = blockIdx.x, t = threadIdx.x;
    if (t < 128) spx[t] = sp_f(ws[O_CRYS + (size_t)b * 128 + t]);
    __syncthreads();
    float acc = fc1b[t];
    for (int k = 0; k < 128; k++) acc += spx[k] * fc1W[k * 256 + t];
    h1[t] = sp_f(acc);
    __syncthreads();
    acc = fc2b[t];
    for (int k = 0; k < 256; k++) acc += h1[k] * fc2W[k * 256 + t];
    h2[t] = sp_f(acc);
    __syncthreads();
    float p = h2[t] * outW[t];
    for (int off = 32; off > 0; off >>= 1) p += __shfl_down(p, off, 64);
    if ((t & 63) == 0) rr[t >> 6] = p;
    __syncthreads();
    if (t == 0) out[b] = rr[0] + rr[1] + rr[2] + rr[3] + outb[0];
}

extern "C" void kernel_launch(void* const* d_in, const int* in_sizes, int n_in,
                              void* d_out, int out_size, void* d_ws, size_t ws_size,
                              hipStream_t stream) {
    const float* af   = (const float*)d_in[0];
    const float* nbr  = (const float*)d_in[1];
    const int*   eidx = (const int*)d_in[2];
    const int*   cidx = (const int*)d_in[3];
    const float* embW = (const float*)d_in[4];
    const float* embB = (const float*)d_in[5];
    const float* convW= (const float*)d_in[6];
    // d_in[7] = conv_b: cancels exactly in the weighted BN that follows the conv GEMM
    const float* bn1g = (const float*)d_in[8];
    const float* bn1b = (const float*)d_in[9];
    const float* bn2g = (const float*)d_in[10];
    const float* bn2b = (const float*)d_in[11];
    const float* fc1W = (const float*)d_in[12];
    const float* fc1b = (const float*)d_in[13];
    const float* fc2W = (const float*)d_in[14];
    const float* fc2b = (const float*)d_in[15];
    const float* outW = (const float*)d_in[16];
    const float* outb = (const float*)d_in[17];
    float* ws = (float*)d_ws;
    float* out = (float*)d_out;

    // zero: SWA/SWC region + crys
    hipMemsetAsync(ws + O_STAT + 1792, 0, (size_t)(2304 + 51200) * sizeof(float), stream);
    k_embed<<<1250, 128, 0, stream>>>(af, embW, embB, ws);
    k_pool1<<<157, 256, 0, stream>>>(cidx, ws);

    // CSR build (per call; ws is re-poisoned before every timed launch)
    hipMemsetAsync(ws + O_DEG, 0, (size_t)40000 * sizeof(int), stream);
    k_hist<<<1563, 256, 0, stream>>>(eidx, ws);
    k_scan<<<1, 1024, 0, stream>>>(ws);
    hipMemsetAsync(ws + O_DEG, 0, (size_t)40000 * sizeof(int), stream);
    k_scatter<<<1563, 256, 0, stream>>>(eidx, ws);

    for (int i = 0; i < 3; i++) {
        hipMemsetAsync(ws + O_STAT, 0, (size_t)772 * sizeof(float), stream);
        const float* Wi = convW + (size_t)i * 297 * 256;
        k_xcat<<<1250, 256, 0, stream>>>(Wi, ws);
        k_edge0<<<3125, 256, 0, stream>>>(nbr, eidx, Wi, ws);
        k_fin1<<<1, 256, 0, stream>>>(bn1g + i * 256, bn1b + i * 256, ws);
        k_msg_atom<<<40000, 256, 0, stream>>>(nbr, eidx, Wi, ws);
        k_stats2<<<256, 256, 0, stream>>>(ws);
        k_fin2<<<1, 128, 0, stream>>>(bn2g + i * 128, bn2b + i * 128, ws);
        k_updx<<<5000, 256, 0, stream>>>(ws);
    }
    k_pool2<<<20000, 256, 0, stream>>>(cidx, ws);
    k_head<<<400, 256, 0, stream>>>(fc1W, fc1b, fc2W, fc2b, outW, outb, ws, out);
}

// Round 6
// 3431.076 us; speedup vs baseline: 1.1884x; 1.1884x over previous
//
#include <hip/hip_runtime.h>
#include <hip/hip_fp16.h>
#include <math.h>

#define NATOMS 40000
#define NEDGE  400000
#define NCRYS  400

// ---- workspace layout (float-slot offsets); high-water ~18,021,504 floats = 72.1 MB ----
#define O_W    0                        // weights[40000] fp32
#define O_X    40960                    // x[40000*128] fp16 (2,560,000 slots)
#define O_XCAT 2600960                  // xcat[40000*512] fp16 (10,240,000 slots)
#define O_SUM  12840960                 // summed[40000*128] fp32
#define O_STAT 17960960                 // stats block [4096]
#define O_CRYS 17965056                 // crys[400*128] fp32
#define O_WH   18016256                 // We fp16 [41*256] (5248 slots)
// stat indices (within O_STAT)
#define S1SUM 0      // [0,256)
#define S1SQ  256    // [256,512)
#define S2SUM 512    // [512,640)
#define S2SQ  640    // [640,768)
#define SWE   768
// per-conv zero region = [0, 772)
#define SC1   1024   // [1024,1280)
#define SH1   1280   // [1280,1536)
#define SC2   1536   // [1536,1664)
#define SH2   1664   // [1664,1792)
#define SWA   1792
#define SWC   1800   // [1800,2200)
// startup zero region = [1792, 4096) + crys

__device__ __forceinline__ float sp_f(float v) {
    return fmaxf(v, 0.f) + log1pf(expf(-fabsf(v)));
}
__device__ __forceinline__ float sig_f(float v) {
    return 1.f / (1.f + expf(-v));
}
__device__ __forceinline__ unsigned pack_h2(float a, float b) {
    __half2 h = __floats2half2_rn(a, b);
    return *reinterpret_cast<unsigned*>(&h);
}
__device__ __forceinline__ void ld4h(const __half* p, float* o) {
    int2 r = *reinterpret_cast<const int2*>(p);
    __half2 h0 = *reinterpret_cast<const __half2*>(&r.x);
    __half2 h1 = *reinterpret_cast<const __half2*>(&r.y);
    float2 f0 = __half22float2(h0), f1 = __half22float2(h1);
    o[0] = f0.x; o[1] = f0.y; o[2] = f1.x; o[3] = f1.y;
}
__device__ __forceinline__ void st4h(__half* p, const float* v) {
    uint2 pk;
    pk.x = pack_h2(v[0], v[1]); pk.y = pack_h2(v[2], v[3]);
    *reinterpret_cast<uint2*>(p) = pk;
}

// ---- embedding: weights[a]=af[a][0]; x = af[:,1:] @ embW + embB (x stored fp16) ----
__global__ __launch_bounds__(128) void k_embed(const float* __restrict__ af,
        const float* __restrict__ embW, const float* __restrict__ embB,
        float* __restrict__ ws) {
    __shared__ float at[93 * 36];   // transposed: at[k*36+m], 32 atoms/block
    int a0 = blockIdx.x * 32;
    int tid = threadIdx.x;
    for (int p = tid; p < 32 * 93; p += 128) {
        int m = p / 93, k = p - m * 93;
        at[k * 36 + m] = af[(size_t)a0 * 93 + p];
    }
    __syncthreads();
    int cq = tid & 31;   // cols cq*4..+3
    int ag = tid >> 5;   // atoms ag*8..+7
    float acc[8][4];
    float4 bb = *reinterpret_cast<const float4*>(&embB[cq * 4]);
    #pragma unroll
    for (int m = 0; m < 8; m++) { acc[m][0] = bb.x; acc[m][1] = bb.y; acc[m][2] = bb.z; acc[m][3] = bb.w; }
    for (int k = 0; k < 92; k++) {
        float4 wv = *reinterpret_cast<const float4*>(&embW[k * 128 + cq * 4]);
        const float* arow = &at[(k + 1) * 36 + ag * 8];
        #pragma unroll
        for (int m = 0; m < 8; m++) {
            float av = arow[m];
            acc[m][0] += av * wv.x; acc[m][1] += av * wv.y;
            acc[m][2] += av * wv.z; acc[m][3] += av * wv.w;
        }
    }
    __half* xh = reinterpret_cast<__half*>(ws + O_X);
    #pragma unroll
    for (int m = 0; m < 8; m++) {
        int a = a0 + ag * 8 + m;
        st4h(&xh[(size_t)a * 128 + cq * 4], acc[m]);
    }
    if (tid < 32) ws[O_W + a0 + tid] = at[0 * 36 + tid];
    if (tid == 0) {
        float s = 0.f;
        for (int m = 0; m < 32; m++) s += at[0 * 36 + m];
        atomicAdd(&ws[O_STAT + SWA], s);
    }
}

// ---- We (rows 256..296 of conv W) -> fp16 in ws ----
__global__ void k_wh(const float* __restrict__ Wi, float* __restrict__ ws) {
    int i = blockIdx.x * 256 + threadIdx.x;   // 41*256 = 10496
    __half* wh = reinterpret_cast<__half*>(ws + O_WH);
    if (i < 41 * 256) wh[i] = __float2half(Wi[256 * 256 + i]);
}

// ---- xcat = x @ [Wa | Wb]  -> fp16 (per conv) ----
__global__ __launch_bounds__(256) void k_xcat(const float* __restrict__ Wi,
        float* __restrict__ ws) {
    __shared__ float xt[128 * 36];   // xt[k*36+m], 32 atoms
    const __half* xh = reinterpret_cast<const __half*>(ws + O_X);
    __half* xcp = reinterpret_cast<__half*>(ws + O_XCAT);
    int a0 = blockIdx.x * 32;
    int tid = threadIdx.x;
    for (int p = tid * 4; p < 32 * 128; p += 1024) {
        float v4[4];
        ld4h(&xh[(size_t)a0 * 128 + p], v4);
        int m = p >> 7, k = p & 127;
        xt[k * 36 + m] = v4[0]; xt[(k + 1) * 36 + m] = v4[1];
        xt[(k + 2) * 36 + m] = v4[2]; xt[(k + 3) * 36 + m] = v4[3];
    }
    __syncthreads();
    int cq = tid & 63, ag = tid >> 6;
    int hb = cq >> 5;            // 0: xa (W rows 0..127), 1: xb (W rows 128..255)
    int c0 = (cq & 31) * 8;      // col within half
    const float* Wp = Wi + (size_t)hb * 128 * 256;
    float acc[8][8];
    #pragma unroll
    for (int m = 0; m < 8; m++)
        #pragma unroll
        for (int j = 0; j < 8; j++) acc[m][j] = 0.f;
    for (int k = 0; k < 128; k++) {
        float4 w0 = *reinterpret_cast<const float4*>(&Wp[k * 256 + c0]);
        float4 w1 = *reinterpret_cast<const float4*>(&Wp[k * 256 + c0 + 4]);
        const float* xr = &xt[k * 36 + ag * 8];
        #pragma unroll
        for (int m = 0; m < 8; m++) {
            float xv = xr[m];
            acc[m][0] += xv * w0.x; acc[m][1] += xv * w0.y;
            acc[m][2] += xv * w0.z; acc[m][3] += xv * w0.w;
            acc[m][4] += xv * w1.x; acc[m][5] += xv * w1.y;
            acc[m][6] += xv * w1.z; acc[m][7] += xv * w1.w;
        }
    }
    #pragma unroll
    for (int m = 0; m < 8; m++) {
        int a = a0 + ag * 8 + m;
        uint4 pk;
        pk.x = pack_h2(acc[m][0], acc[m][1]);
        pk.y = pack_h2(acc[m][2], acc[m][3]);
        pk.z = pack_h2(acc[m][4], acc[m][5]);
        pk.w = pack_h2(acc[m][6], acc[m][7]);
        *reinterpret_cast<uint4*>(&xcp[(size_t)a * 512 + hb * 256 + c0]) = pk;
    }
}

// ---- BN1 stats pass: g = e@We + xa[i0] + xb[i1]; weighted sums (no store of g) ----
__global__ __launch_bounds__(256) void k_edge0(const float* __restrict__ nbr,
        const int* __restrict__ eidx, float* __restrict__ ws) {
    __shared__ float lds[4352];      // et[41*64]=2624; reused as red[4096]
    __shared__ float wl[64];
    __shared__ int i0l[64], i1l[64];
    float* st = ws + O_STAT;
    const __half* xc = reinterpret_cast<const __half*>(ws + O_XCAT);
    const __half* wh = reinterpret_cast<const __half*>(ws + O_WH);
    int tid = threadIdx.x;
    int cq = tid & 31, eq = tid >> 5;

    float sF[4] = {0,0,0,0}, sC[4] = {0,0,0,0}, qF[4] = {0,0,0,0}, qC[4] = {0,0,0,0};
    float swe_acc = 0.f;
    for (int g = 0; g < 2; ++g) {
        int e0 = (blockIdx.x + g * 3125) * 64;
        __syncthreads();   // protect lds reuse from previous tile
        for (int q = tid; q < 672; q += 256) {
            float4 v = *reinterpret_cast<const float4*>(&nbr[(size_t)e0 * 42 + q * 4]);
            float va[4] = {v.x, v.y, v.z, v.w};
            #pragma unroll
            for (int j = 0; j < 4; j++) {
                int p = q * 4 + j;
                int m = p / 42;
                int k = p - m * 42;
                if (k < 41) lds[k * 64 + m] = va[j]; else wl[m] = va[j];
            }
        }
        if (tid < 64) {
            i0l[tid] = eidx[(size_t)(e0 + tid) * 2];
            i1l[tid] = eidx[(size_t)(e0 + tid) * 2 + 1];
        }
        __syncthreads();

        float ef[8][4], ec[8][4];
        #pragma unroll
        for (int m = 0; m < 8; m++)
            #pragma unroll
            for (int j = 0; j < 4; j++) { ef[m][j] = 0.f; ec[m][j] = 0.f; }
        for (int k = 0; k < 41; k++) {
            float wf[4], wc[4];
            ld4h(&wh[k * 256 + cq * 4], wf);
            ld4h(&wh[k * 256 + 128 + cq * 4], wc);
            const float* ev = &lds[k * 64 + eq * 8];
            #pragma unroll
            for (int m = 0; m < 8; m++) {
                float e = ev[m];
                ef[m][0] += e * wf[0]; ef[m][1] += e * wf[1];
                ef[m][2] += e * wf[2]; ef[m][3] += e * wf[3];
                ec[m][0] += e * wc[0]; ec[m][1] += e * wc[1];
                ec[m][2] += e * wc[2]; ec[m][3] += e * wc[3];
            }
        }
        #pragma unroll
        for (int m = 0; m < 8; m++) {
            int em = eq * 8 + m;
            int i0 = i0l[em], i1 = i1l[em];
            float xaf[4], xac[4], xbf[4], xbc[4];
            ld4h(&xc[(size_t)i0 * 512 + cq * 4], xaf);
            ld4h(&xc[(size_t)i0 * 512 + 128 + cq * 4], xac);
            ld4h(&xc[(size_t)i1 * 512 + 256 + cq * 4], xbf);
            ld4h(&xc[(size_t)i1 * 512 + 384 + cq * 4], xbc);
            float w = wl[em];
            #pragma unroll
            for (int j = 0; j < 4; j++) {
                float gf = ef[m][j] + xaf[j] + xbf[j];
                float gc = ec[m][j] + xac[j] + xbc[j];
                float tf = w * gf, tc = w * gc;
                sF[j] += tf; qF[j] += tf * gf;
                sC[j] += tc; qC[j] += tc * gc;
            }
        }
        if (tid == 0) {
            float s = 0.f;
            for (int m = 0; m < 64; m++) s += wl[m];
            swe_acc += s;
        }
    }
    __syncthreads();
    #pragma unroll
    for (int j = 0; j < 4; j++) {
        lds[eq * 512 + cq * 4 + j]       = sF[j];
        lds[eq * 512 + 128 + cq * 4 + j] = sC[j];
        lds[eq * 512 + 256 + cq * 4 + j] = qF[j];
        lds[eq * 512 + 384 + cq * 4 + j] = qC[j];
    }
    __syncthreads();
    for (int pos = tid; pos < 512; pos += 256) {
        float v = 0.f;
        #pragma unroll
        for (int q8 = 0; q8 < 8; q8++) v += lds[q8 * 512 + pos];
        atomicAdd(&st[pos], v);
    }
    if (tid == 0) atomicAdd(&st[SWE], swe_acc);
}

__global__ void k_fin1(const float* __restrict__ bn1g, const float* __restrict__ bn1b,
        float* __restrict__ ws) {
    float* st = ws + O_STAT;
    int c = threadIdx.x;  // 256
    float sw = st[SWE];
    float mean = st[S1SUM + c] / sw;
    float var = st[S1SQ + c] / sw - mean * mean;
    float sc = bn1g[c] / sqrtf(var + 1e-5f);
    st[SC1 + c] = sc;
    st[SH1 + c] = bn1b[c] - mean * sc;
}

// ---- apply pass: recompute g, BN1, msg = sig(f)*sp(c), atomic scatter-add ----
__global__ __launch_bounds__(256) void k_edge1(const float* __restrict__ nbr,
        const int* __restrict__ eidx, float* __restrict__ ws) {
    __shared__ float lds[2624];      // et[41*64]
    __shared__ int i0l[64], i1l[64];
    const float* st = ws + O_STAT;
    float* summed = ws + O_SUM;
    const __half* xc = reinterpret_cast<const __half*>(ws + O_XCAT);
    const __half* wh = reinterpret_cast<const __half*>(ws + O_WH);
    int tid = threadIdx.x;
    int cq = tid & 31, eq = tid >> 5;
    int e0 = blockIdx.x * 64;

    float scf[4], shf[4], scc[4], shc[4];
    #pragma unroll
    for (int j = 0; j < 4; j++) {
        scf[j] = st[SC1 + cq * 4 + j];
        shf[j] = st[SH1 + cq * 4 + j];
        scc[j] = st[SC1 + 128 + cq * 4 + j];
        shc[j] = st[SH1 + 128 + cq * 4 + j];
    }
    for (int q = tid; q < 672; q += 256) {
        float4 v = *reinterpret_cast<const float4*>(&nbr[(size_t)e0 * 42 + q * 4]);
        float va[4] = {v.x, v.y, v.z, v.w};
        #pragma unroll
        for (int j = 0; j < 4; j++) {
            int p = q * 4 + j;
            int m = p / 42;
            int k = p - m * 42;
            if (k < 41) lds[k * 64 + m] = va[j];
        }
    }
    if (tid < 64) {
        i0l[tid] = eidx[(size_t)(e0 + tid) * 2];
        i1l[tid] = eidx[(size_t)(e0 + tid) * 2 + 1];
    }
    __syncthreads();

    float ef[8][4], ec[8][4];
    #pragma unroll
    for (int m = 0; m < 8; m++)
        #pragma unroll
        for (int j = 0; j < 4; j++) { ef[m][j] = 0.f; ec[m][j] = 0.f; }
    for (int k = 0; k < 41; k++) {
        float wf[4], wc[4];
        ld4h(&wh[k * 256 + cq * 4], wf);
        ld4h(&wh[k * 256 + 128 + cq * 4], wc);
        const float* ev = &lds[k * 64 + eq * 8];
        #pragma unroll
        for (int m = 0; m < 8; m++) {
            float e = ev[m];
            ef[m][0] += e * wf[0]; ef[m][1] += e * wf[1];
            ef[m][2] += e * wf[2]; ef[m][3] += e * wf[3];
            ec[m][0] += e * wc[0]; ec[m][1] += e * wc[1];
            ec[m][2] += e * wc[2]; ec[m][3] += e * wc[3];
        }
    }
    #pragma unroll
    for (int m = 0; m < 8; m++) {
        int em = eq * 8 + m;
        int i0 = i0l[em], i1 = i1l[em];
        float xaf[4], xac[4], xbf[4], xbc[4];
        ld4h(&xc[(size_t)i0 * 512 + cq * 4], xaf);
        ld4h(&xc[(size_t)i0 * 512 + 128 + cq * 4], xac);
        ld4h(&xc[(size_t)i1 * 512 + 256 + cq * 4], xbf);
        ld4h(&xc[(size_t)i1 * 512 + 384 + cq * 4], xbc);
        #pragma unroll
        for (int j = 0; j < 4; j++) {
            float gf = ef[m][j] + xaf[j] + xbf[j];
            float gc = ec[m][j] + xac[j] + xbc[j];
            float fn = gf * scf[j] + shf[j];
            float cn = gc * scc[j] + shc[j];
            float msg = sig_f(fn) * sp_f(cn);
            atomicAdd(&summed[(size_t)i0 * 128 + cq * 4 + j], msg);
        }
    }
}

__global__ __launch_bounds__(256) void k_stats2(float* __restrict__ ws) {
    const float* sm = ws + O_SUM;
    const float* w = ws + O_W;
    float* st = ws + O_STAT;
    int tid = threadIdx.x;
    int c = tid & 127, r = tid >> 7;
    float s = 0.f, q = 0.f;
    for (int a = blockIdx.x * 2 + r; a < NATOMS; a += 512) {
        float wa = w[a];
        float v = sm[(size_t)a * 128 + c];
        s += wa * v; q += wa * v * v;
    }
    __shared__ float rs[256], rq[256];
    rs[tid] = s; rq[tid] = q;
    __syncthreads();
    if (r == 0) {
        atomicAdd(&st[S2SUM + c], s + rs[tid + 128]);
        atomicAdd(&st[S2SQ + c], q + rq[tid + 128]);
    }
}

__global__ void k_fin2(const float* __restrict__ bn2g, const float* __restrict__ bn2b,
        float* __restrict__ ws) {
    float* st = ws + O_STAT;
    int c = threadIdx.x;  // 128
    float sw = st[SWA];
    float mean = st[S2SUM + c] / sw;
    float var = st[S2SQ + c] / sw - mean * mean;
    float sc = bn2g[c] / sqrtf(var + 1e-5f);
    st[SC2 + c] = sc;
    st[SH2 + c] = bn2b[c] - mean * sc;
}

__global__ __launch_bounds__(256) void k_updx(float* __restrict__ ws) {
    __half* xh = reinterpret_cast<__half*>(ws + O_X);
    const float* sm = ws + O_SUM;
    const float* st = ws + O_STAT;
    int i = blockIdx.x * 256 + threadIdx.x;   // 4-elem group index, 1,280,000 total
    int c4 = (i & 31) * 4;
    float xv[4];
    ld4h(&xh[(size_t)i * 4], xv);
    float4 sv = *reinterpret_cast<const float4*>(&sm[(size_t)i * 4]);
    float4 sc = *reinterpret_cast<const float4*>(&st[SC2 + c4]);
    float4 sh = *reinterpret_cast<const float4*>(&st[SH2 + c4]);
    float o[4];
    o[0] = sp_f(xv[0] + sv.x * sc.x + sh.x);
    o[1] = sp_f(xv[1] + sv.y * sc.y + sh.y);
    o[2] = sp_f(xv[2] + sv.z * sc.z + sh.z);
    o[3] = sp_f(xv[3] + sv.w * sc.w + sh.w);
    st4h(&xh[(size_t)i * 4], o);
}

__global__ void k_pool1(const int* __restrict__ cidx, float* __restrict__ ws) {
    int a = blockIdx.x * 256 + threadIdx.x;
    if (a < NATOMS) atomicAdd(&ws[O_STAT + SWC + cidx[a]], ws[O_W + a]);
}

__global__ void k_pool2(const int* __restrict__ cidx, float* __restrict__ ws) {
    int i = blockIdx.x * 256 + threadIdx.x;   // 5,120,000
    int a = i >> 7, c = i & 127;
    int s = cidx[a];
    const __half* xh = reinterpret_cast<const __half*>(ws + O_X);
    float coef = ws[O_W + a] / ws[O_STAT + SWC + s];
    atomicAdd(&ws[O_CRYS + (size_t)s * 128 + c], coef * __half2float(xh[(size_t)i]));
}

__global__ __launch_bounds__(256) void k_head(const float* __restrict__ fc1W,
        const float* __restrict__ fc1b, const float* __restrict__ fc2W,
        const float* __restrict__ fc2b, const float* __restrict__ outW,
        const float* __restrict__ outb, const float* __restrict__ ws,
        float* __restrict__ out) {
    __shared__ float spx[128], h1[256], h2[256], rr[4];
    int b = blockIdx.x, t = threadIdx.x;
    if (t < 128) spx[t] = sp_f(ws[O_CRYS + (size_t)b * 128 + t]);
    __syncthreads();
    float acc = fc1b[t];
    for (int k = 0; k < 128; k++) acc += spx[k] * fc1W[k * 256 + t];
    h1[t] = sp_f(acc);
    __syncthreads();
    acc = fc2b[t];
    for (int k = 0; k < 256; k++) acc += h1[k] * fc2W[k * 256 + t];
    h2[t] = sp_f(acc);
    __syncthreads();
    float p = h2[t] * outW[t];
    for (int off = 32; off > 0; off >>= 1) p += __shfl_down(p, off, 64);
    if ((t & 63) == 0) rr[t >> 6] = p;
    __syncthreads();
    if (t == 0) out[b] = rr[0] + rr[1] + rr[2] + rr[3] + outb[0];
}

extern "C" void kernel_launch(void* const* d_in, const int* in_sizes, int n_in,
                              void* d_out, int out_size, void* d_ws, size_t ws_size,
                              hipStream_t stream) {
    const float* af   = (const float*)d_in[0];
    const float* nbr  = (const float*)d_in[1];
    const int*   eidx = (const int*)d_in[2];
    const int*   cidx = (const int*)d_in[3];
    const float* embW = (const float*)d_in[4];
    const float* embB = (const float*)d_in[5];
    const float* convW= (const float*)d_in[6];
    // d_in[7] = conv_b: cancels exactly in the weighted BN that follows the conv GEMM
    const float* bn1g = (const float*)d_in[8];
    const float* bn1b = (const float*)d_in[9];
    const float* bn2g = (const float*)d_in[10];
    const float* bn2b = (const float*)d_in[11];
    const float* fc1W = (const float*)d_in[12];
    const float* fc1b = (const float*)d_in[13];
    const float* fc2W = (const float*)d_in[14];
    const float* fc2b = (const float*)d_in[15];
    const float* outW = (const float*)d_in[16];
    const float* outb = (const float*)d_in[17];
    float* ws = (float*)d_ws;
    float* out = (float*)d_out;

    // zero: SWA/SWC region + crys
    hipMemsetAsync(ws + O_STAT + 1792, 0, (size_t)(2304 + 51200) * sizeof(float), stream);
    k_embed<<<1250, 128, 0, stream>>>(af, embW, embB, ws);
    k_pool1<<<157, 256, 0, stream>>>(cidx, ws);

    for (int i = 0; i < 3; i++) {
        hipMemsetAsync(ws + O_SUM, 0, (size_t)5120000 * sizeof(float), stream);
        hipMemsetAsync(ws + O_STAT, 0, (size_t)772 * sizeof(float), stream);
        const float* Wi = convW + (size_t)i * 297 * 256;
        k_wh<<<41, 256, 0, stream>>>(Wi, ws);
        k_xcat<<<1250, 256, 0, stream>>>(Wi, ws);
        k_edge0<<<3125, 256, 0, stream>>>(nbr, eidx, ws);
        k_fin1<<<1, 256, 0, stream>>>(bn1g + i * 256, bn1b + i * 256, ws);
        k_edge1<<<6250, 256, 0, stream>>>(nbr, eidx, ws);
        k_stats2<<<256, 256, 0, stream>>>(ws);
        k_fin2<<<1, 128, 0, stream>>>(bn2g + i * 128, bn2b + i * 128, ws);
        k_updx<<<5000, 256, 0, stream>>>(ws);
    }
    k_pool2<<<20000, 256, 0, stream>>>(cidx, ws);
    k_head<<<400, 256, 0, stream>>>(fc1W, fc1b, fc2W, fc2b, outW, outb, ws, out);
}

// Round 7
// 2445.240 us; speedup vs baseline: 1.6675x; 1.4032x over previous
//
#include <hip/hip_runtime.h>
#include <hip/hip_fp16.h>
#include <math.h>

#define NATOMS 40000
#define NEDGE  400000
#define NCRYS  400

// ---- workspace layout (float-slot offsets); high-water ~18,501,632 floats = 74.0 MB ----
#define O_W    0                        // weights[40000] fp32
#define O_X    40960                    // x[40000*128] fp16 (2,560,000 slots)
#define O_XCAT 2600960                  // xcat[40000*512] fp16 (10,240,000 slots)
#define O_SUM  12840960                 // summed[40000*128] fp32
#define O_STAT 17960960                 // stats block [4096]
#define O_CRYS 17965056                 // crys[400*128] fp32
#define O_WH   18016256                 // We fp16 [41*256] (5248 slots)
#define O_PTR  18021504                 // CSR row ptr [40001] int (pad to 40064)
#define O_DEG  18061568                 // degree/cursor [40000] int
#define O_EORD 18101568                 // edge order [400000] int
// stat indices (within O_STAT)
#define S1SUM 0      // [0,256)
#define S1SQ  256    // [256,512)
#define S2SUM 512    // [512,640)
#define S2SQ  640    // [640,768)
#define SWE   768
// per-conv zero region = [0, 772)
#define SC1   1024   // [1024,1280)
#define SH1   1280   // [1280,1536)
#define SC2   1536   // [1536,1664)
#define SH2   1664   // [1664,1792)
#define SWA   1792
#define SWC   1800   // [1800,2200)
// startup zero region = [1792, 4096) + crys

__device__ __forceinline__ float sp_f(float v) {
    return fmaxf(v, 0.f) + log1pf(expf(-fabsf(v)));
}
__device__ __forceinline__ float sig_f(float v) {
    return 1.f / (1.f + expf(-v));
}
__device__ __forceinline__ unsigned pack_h2(float a, float b) {
    __half2 h = __floats2half2_rn(a, b);
    return *reinterpret_cast<unsigned*>(&h);
}
__device__ __forceinline__ void ld4h(const __half* p, float* o) {
    int2 r = *reinterpret_cast<const int2*>(p);
    __half2 h0 = *reinterpret_cast<const __half2*>(&r.x);
    __half2 h1 = *reinterpret_cast<const __half2*>(&r.y);
    float2 f0 = __half22float2(h0), f1 = __half22float2(h1);
    o[0] = f0.x; o[1] = f0.y; o[2] = f1.x; o[3] = f1.y;
}
__device__ __forceinline__ void st4h(__half* p, const float* v) {
    uint2 pk;
    pk.x = pack_h2(v[0], v[1]); pk.y = pack_h2(v[2], v[3]);
    *reinterpret_cast<uint2*>(p) = pk;
}

// ---- embedding: weights[a]=af[a][0]; x = af[:,1:] @ embW + embB (x stored fp16) ----
__global__ __launch_bounds__(128) void k_embed(const float* __restrict__ af,
        const float* __restrict__ embW, const float* __restrict__ embB,
        float* __restrict__ ws) {
    __shared__ float at[93 * 36];   // transposed: at[k*36+m], 32 atoms/block
    int a0 = blockIdx.x * 32;
    int tid = threadIdx.x;
    for (int p = tid; p < 32 * 93; p += 128) {
        int m = p / 93, k = p - m * 93;
        at[k * 36 + m] = af[(size_t)a0 * 93 + p];
    }
    __syncthreads();
    int cq = tid & 31;   // cols cq*4..+3
    int ag = tid >> 5;   // atoms ag*8..+7
    float acc[8][4];
    float4 bb = *reinterpret_cast<const float4*>(&embB[cq * 4]);
    #pragma unroll
    for (int m = 0; m < 8; m++) { acc[m][0] = bb.x; acc[m][1] = bb.y; acc[m][2] = bb.z; acc[m][3] = bb.w; }
    for (int k = 0; k < 92; k++) {
        float4 wv = *reinterpret_cast<const float4*>(&embW[k * 128 + cq * 4]);
        const float* arow = &at[(k + 1) * 36 + ag * 8];
        #pragma unroll
        for (int m = 0; m < 8; m++) {
            float av = arow[m];
            acc[m][0] += av * wv.x; acc[m][1] += av * wv.y;
            acc[m][2] += av * wv.z; acc[m][3] += av * wv.w;
        }
    }
    __half* xh = reinterpret_cast<__half*>(ws + O_X);
    #pragma unroll
    for (int m = 0; m < 8; m++) {
        int a = a0 + ag * 8 + m;
        st4h(&xh[(size_t)a * 128 + cq * 4], acc[m]);
    }
    if (tid < 32) ws[O_W + a0 + tid] = at[0 * 36 + tid];
    if (tid == 0) {
        float s = 0.f;
        for (int m = 0; m < 32; m++) s += at[0 * 36 + m];
        atomicAdd(&ws[O_STAT + SWA], s);
    }
}

// ---- We (rows 256..296 of conv W) -> fp16 in ws ----
__global__ void k_wh(const float* __restrict__ Wi, float* __restrict__ ws) {
    int i = blockIdx.x * 256 + threadIdx.x;   // 41*256 = 10496
    __half* wh = reinterpret_cast<__half*>(ws + O_WH);
    if (i < 41 * 256) wh[i] = __float2half(Wi[256 * 256 + i]);
}

// ---- CSR build: hist -> scan -> scatter (destination = i0) ----
__global__ void k_hist(const int* __restrict__ eidx, float* __restrict__ ws) {
    int e = blockIdx.x * 256 + threadIdx.x;
    int* deg = (int*)(ws + O_DEG);
    if (e < NEDGE) atomicAdd(&deg[eidx[(size_t)e * 2]], 1);
}

__global__ __launch_bounds__(1024) void k_scan(float* __restrict__ ws) {
    const int* deg = (const int*)(ws + O_DEG);
    int* ptr = (int*)(ws + O_PTR);
    __shared__ int buf[1024];
    __shared__ int carry;
    int t = threadIdx.x;
    if (t == 0) carry = 0;
    __syncthreads();
    for (int c = 0; c < 40; c++) {
        int i = c * 1024 + t;
        int v = (i < NATOMS) ? deg[i] : 0;
        buf[t] = v;
        __syncthreads();
        for (int off = 1; off < 1024; off <<= 1) {
            int u = (t >= off) ? buf[t - off] : 0;
            __syncthreads();
            buf[t] += u;
            __syncthreads();
        }
        int inc = buf[t];
        if (i < NATOMS) ptr[i] = carry + inc - v;   // exclusive scan
        __syncthreads();
        if (t == 1023) carry += inc;
        __syncthreads();
    }
    if (t == 0) ptr[NATOMS] = carry;
}

__global__ void k_scatter(const int* __restrict__ eidx, float* __restrict__ ws) {
    int e = blockIdx.x * 256 + threadIdx.x;
    if (e >= NEDGE) return;
    const int* ptr = (const int*)(ws + O_PTR);
    int* cur = (int*)(ws + O_DEG);            // re-zeroed before this kernel
    int* eord = (int*)(ws + O_EORD);
    int i0 = eidx[(size_t)e * 2];
    int pos = ptr[i0] + atomicAdd(&cur[i0], 1);
    eord[pos] = e;
}

// ---- xcat = x @ [Wa | Wb]  -> fp16 (per conv) ----
__global__ __launch_bounds__(256) void k_xcat(const float* __restrict__ Wi,
        float* __restrict__ ws) {
    __shared__ float xt[128 * 36];   // xt[k*36+m], 32 atoms
    const __half* xh = reinterpret_cast<const __half*>(ws + O_X);
    __half* xcp = reinterpret_cast<__half*>(ws + O_XCAT);
    int a0 = blockIdx.x * 32;
    int tid = threadIdx.x;
    for (int p = tid * 4; p < 32 * 128; p += 1024) {
        float v4[4];
        ld4h(&xh[(size_t)a0 * 128 + p], v4);
        int m = p >> 7, k = p & 127;
        xt[k * 36 + m] = v4[0]; xt[(k + 1) * 36 + m] = v4[1];
        xt[(k + 2) * 36 + m] = v4[2]; xt[(k + 3) * 36 + m] = v4[3];
    }
    __syncthreads();
    int cq = tid & 63, ag = tid >> 6;
    int hb = cq >> 5;            // 0: xa (W rows 0..127), 1: xb (W rows 128..255)
    int c0 = (cq & 31) * 8;      // col within half
    const float* Wp = Wi + (size_t)hb * 128 * 256;
    float acc[8][8];
    #pragma unroll
    for (int m = 0; m < 8; m++)
        #pragma unroll
        for (int j = 0; j < 8; j++) acc[m][j] = 0.f;
    for (int k = 0; k < 128; k++) {
        float4 w0 = *reinterpret_cast<const float4*>(&Wp[k * 256 + c0]);
        float4 w1 = *reinterpret_cast<const float4*>(&Wp[k * 256 + c0 + 4]);
        const float* xr = &xt[k * 36 + ag * 8];
        #pragma unroll
        for (int m = 0; m < 8; m++) {
            float xv = xr[m];
            acc[m][0] += xv * w0.x; acc[m][1] += xv * w0.y;
            acc[m][2] += xv * w0.z; acc[m][3] += xv * w0.w;
            acc[m][4] += xv * w1.x; acc[m][5] += xv * w1.y;
            acc[m][6] += xv * w1.z; acc[m][7] += xv * w1.w;
        }
    }
    #pragma unroll
    for (int m = 0; m < 8; m++) {
        int a = a0 + ag * 8 + m;
        uint4 pk;
        pk.x = pack_h2(acc[m][0], acc[m][1]);
        pk.y = pack_h2(acc[m][2], acc[m][3]);
        pk.z = pack_h2(acc[m][4], acc[m][5]);
        pk.w = pack_h2(acc[m][6], acc[m][7]);
        *reinterpret_cast<uint4*>(&xcp[(size_t)a * 512 + hb * 256 + c0]) = pk;
    }
}

// ---- BN1 stats pass: g = e@We + xa[i0] + xb[i1]; weighted sums (no store of g) ----
__global__ __launch_bounds__(256) void k_edge0(const float* __restrict__ nbr,
        const int* __restrict__ eidx, float* __restrict__ ws) {
    __shared__ float lds[4352];      // et[41*64]=2624; reused as red[4096]
    __shared__ float wl[64];
    __shared__ int i0l[64], i1l[64];
    float* st = ws + O_STAT;
    const __half* xc = reinterpret_cast<const __half*>(ws + O_XCAT);
    const __half* wh = reinterpret_cast<const __half*>(ws + O_WH);
    int tid = threadIdx.x;
    int cq = tid & 31, eq = tid >> 5;

    float sF[4] = {0,0,0,0}, sC[4] = {0,0,0,0}, qF[4] = {0,0,0,0}, qC[4] = {0,0,0,0};
    float swe_acc = 0.f;
    for (int g = 0; g < 2; ++g) {
        int e0 = (blockIdx.x + g * 3125) * 64;
        __syncthreads();   // protect lds reuse from previous tile
        for (int q = tid; q < 672; q += 256) {
            float4 v = *reinterpret_cast<const float4*>(&nbr[(size_t)e0 * 42 + q * 4]);
            float va[4] = {v.x, v.y, v.z, v.w};
            #pragma unroll
            for (int j = 0; j < 4; j++) {
                int p = q * 4 + j;
                int m = p / 42;
                int k = p - m * 42;
                if (k < 41) lds[k * 64 + m] = va[j]; else wl[m] = va[j];
            }
        }
        if (tid < 64) {
            i0l[tid] = eidx[(size_t)(e0 + tid) * 2];
            i1l[tid] = eidx[(size_t)(e0 + tid) * 2 + 1];
        }
        __syncthreads();

        float ef[8][4], ec[8][4];
        #pragma unroll
        for (int m = 0; m < 8; m++)
            #pragma unroll
            for (int j = 0; j < 4; j++) { ef[m][j] = 0.f; ec[m][j] = 0.f; }
        for (int k = 0; k < 41; k++) {
            float wf[4], wc[4];
            ld4h(&wh[k * 256 + cq * 4], wf);
            ld4h(&wh[k * 256 + 128 + cq * 4], wc);
            const float* ev = &lds[k * 64 + eq * 8];
            #pragma unroll
            for (int m = 0; m < 8; m++) {
                float e = ev[m];
                ef[m][0] += e * wf[0]; ef[m][1] += e * wf[1];
                ef[m][2] += e * wf[2]; ef[m][3] += e * wf[3];
                ec[m][0] += e * wc[0]; ec[m][1] += e * wc[1];
                ec[m][2] += e * wc[2]; ec[m][3] += e * wc[3];
            }
        }
        #pragma unroll
        for (int m = 0; m < 8; m++) {
            int em = eq * 8 + m;
            int i0 = i0l[em], i1 = i1l[em];
            float xaf[4], xac[4], xbf[4], xbc[4];
            ld4h(&xc[(size_t)i0 * 512 + cq * 4], xaf);
            ld4h(&xc[(size_t)i0 * 512 + 128 + cq * 4], xac);
            ld4h(&xc[(size_t)i1 * 512 + 256 + cq * 4], xbf);
            ld4h(&xc[(size_t)i1 * 512 + 384 + cq * 4], xbc);
            float w = wl[em];
            #pragma unroll
            for (int j = 0; j < 4; j++) {
                float gf = ef[m][j] + xaf[j] + xbf[j];
                float gc = ec[m][j] + xac[j] + xbc[j];
                float tf = w * gf, tc = w * gc;
                sF[j] += tf; qF[j] += tf * gf;
                sC[j] += tc; qC[j] += tc * gc;
            }
        }
        if (tid == 0) {
            float s = 0.f;
            for (int m = 0; m < 64; m++) s += wl[m];
            swe_acc += s;
        }
    }
    __syncthreads();
    #pragma unroll
    for (int j = 0; j < 4; j++) {
        lds[eq * 512 + cq * 4 + j]       = sF[j];
        lds[eq * 512 + 128 + cq * 4 + j] = sC[j];
        lds[eq * 512 + 256 + cq * 4 + j] = qF[j];
        lds[eq * 512 + 384 + cq * 4 + j] = qC[j];
    }
    __syncthreads();
    for (int pos = tid; pos < 512; pos += 256) {
        float v = 0.f;
        #pragma unroll
        for (int q8 = 0; q8 < 8; q8++) v += lds[q8 * 512 + pos];
        atomicAdd(&st[pos], v);
    }
    if (tid == 0) atomicAdd(&st[SWE], swe_acc);
}

__global__ void k_fin1(const float* __restrict__ bn1g, const float* __restrict__ bn1b,
        float* __restrict__ ws) {
    float* st = ws + O_STAT;
    int c = threadIdx.x;  // 256
    float sw = st[SWE];
    float mean = st[S1SUM + c] / sw;
    float var = st[S1SQ + c] / sw - mean * mean;
    float sc = bn1g[c] / sqrtf(var + 1e-5f);
    st[SC1 + c] = sc;
    st[SH1 + c] = bn1b[c] - mean * sc;
}

// ---- apply pass: i0-sorted edges; recompute g, BN1, msg; run-accumulated atomics ----
__global__ __launch_bounds__(256) void k_edge1(const float* __restrict__ nbr,
        const int* __restrict__ eidx, float* __restrict__ ws) {
    __shared__ float lds[2624];      // et[41*64]
    __shared__ int i0l[64], i1l[64], el[64];
    const float* st = ws + O_STAT;
    float* summed = ws + O_SUM;
    const __half* xc = reinterpret_cast<const __half*>(ws + O_XCAT);
    const __half* wh = reinterpret_cast<const __half*>(ws + O_WH);
    const int* eord = (const int*)(ws + O_EORD);
    int tid = threadIdx.x;
    int cq = tid & 31, eq = tid >> 5;
    int e0 = blockIdx.x * 64;

    float scf[4], shf[4], scc[4], shc[4];
    #pragma unroll
    for (int j = 0; j < 4; j++) {
        scf[j] = st[SC1 + cq * 4 + j];
        shf[j] = st[SH1 + cq * 4 + j];
        scc[j] = st[SC1 + 128 + cq * 4 + j];
        shc[j] = st[SH1 + 128 + cq * 4 + j];
    }
    if (tid < 64) {
        int e = eord[e0 + tid];
        el[tid] = e;
        i0l[tid] = eidx[(size_t)e * 2];
        i1l[tid] = eidx[(size_t)e * 2 + 1];
    }
    __syncthreads();
    // gather-stage 64 sorted rows (41 features each; element 41 = weight, unused here)
    for (int q = tid; q < 704; q += 256) {
        int m = q / 11, s = q - m * 11;
        int e = el[m];
        if (s < 10) {
            float4 v = *reinterpret_cast<const float4*>(&nbr[(size_t)e * 42 + s * 4]);
            lds[(s * 4 + 0) * 64 + m] = v.x;
            lds[(s * 4 + 1) * 64 + m] = v.y;
            lds[(s * 4 + 2) * 64 + m] = v.z;
            lds[(s * 4 + 3) * 64 + m] = v.w;
        } else {
            lds[40 * 64 + m] = nbr[(size_t)e * 42 + 40];
        }
    }
    __syncthreads();

    float ef[8][4], ec[8][4];
    #pragma unroll
    for (int m = 0; m < 8; m++)
        #pragma unroll
        for (int j = 0; j < 4; j++) { ef[m][j] = 0.f; ec[m][j] = 0.f; }
    for (int k = 0; k < 41; k++) {
        float wf[4], wc[4];
        ld4h(&wh[k * 256 + cq * 4], wf);
        ld4h(&wh[k * 256 + 128 + cq * 4], wc);
        const float* ev = &lds[k * 64 + eq * 8];
        #pragma unroll
        for (int m = 0; m < 8; m++) {
            float e = ev[m];
            ef[m][0] += e * wf[0]; ef[m][1] += e * wf[1];
            ef[m][2] += e * wf[2]; ef[m][3] += e * wf[3];
            ec[m][0] += e * wc[0]; ec[m][1] += e * wc[1];
            ec[m][2] += e * wc[2]; ec[m][3] += e * wc[3];
        }
    }
    // run-length accumulated scatter (edges sorted by i0)
    int prev = i0l[eq * 8];
    float acc[4] = {0.f, 0.f, 0.f, 0.f};
    #pragma unroll
    for (int m = 0; m < 8; m++) {
        int em = eq * 8 + m;
        int i0 = i0l[em], i1 = i1l[em];
        float xaf[4], xac[4], xbf[4], xbc[4];
        ld4h(&xc[(size_t)i0 * 512 + cq * 4], xaf);
        ld4h(&xc[(size_t)i0 * 512 + 128 + cq * 4], xac);
        ld4h(&xc[(size_t)i1 * 512 + 256 + cq * 4], xbf);
        ld4h(&xc[(size_t)i1 * 512 + 384 + cq * 4], xbc);
        float msg[4];
        #pragma unroll
        for (int j = 0; j < 4; j++) {
            float gf = ef[m][j] + xaf[j] + xbf[j];
            float gc = ec[m][j] + xac[j] + xbc[j];
            float fn = gf * scf[j] + shf[j];
            float cn = gc * scc[j] + shc[j];
            msg[j] = sig_f(fn) * sp_f(cn);
        }
        if (i0 != prev) {
            #pragma unroll
            for (int j = 0; j < 4; j++) {
                atomicAdd(&summed[(size_t)prev * 128 + cq * 4 + j], acc[j]);
                acc[j] = msg[j];
            }
            prev = i0;
        } else {
            #pragma unroll
            for (int j = 0; j < 4; j++) acc[j] += msg[j];
        }
    }
    #pragma unroll
    for (int j = 0; j < 4; j++)
        atomicAdd(&summed[(size_t)prev * 128 + cq * 4 + j], acc[j]);
}

__global__ __launch_bounds__(256) void k_stats2(float* __restrict__ ws) {
    const float* sm = ws + O_SUM;
    const float* w = ws + O_W;
    float* st = ws + O_STAT;
    int tid = threadIdx.x;
    int c = tid & 127, r = tid >> 7;
    float s = 0.f, q = 0.f;
    for (int a = blockIdx.x * 2 + r; a < NATOMS; a += 512) {
        float wa = w[a];
        float v = sm[(size_t)a * 128 + c];
        s += wa * v; q += wa * v * v;
    }
    __shared__ float rs[256], rq[256];
    rs[tid] = s; rq[tid] = q;
    __syncthreads();
    if (r == 0) {
        atomicAdd(&st[S2SUM + c], s + rs[tid + 128]);
        atomicAdd(&st[S2SQ + c], q + rq[tid + 128]);
    }
}

__global__ void k_fin2(const float* __restrict__ bn2g, const float* __restrict__ bn2b,
        float* __restrict__ ws) {
    float* st = ws + O_STAT;
    int c = threadIdx.x;  // 128
    float sw = st[SWA];
    float mean = st[S2SUM + c] / sw;
    float var = st[S2SQ + c] / sw - mean * mean;
    float sc = bn2g[c] / sqrtf(var + 1e-5f);
    st[SC2 + c] = sc;
    st[SH2 + c] = bn2b[c] - mean * sc;
}

__global__ __launch_bounds__(256) void k_updx(float* __restrict__ ws) {
    __half* xh = reinterpret_cast<__half*>(ws + O_X);
    const float* sm = ws + O_SUM;
    const float* st = ws + O_STAT;
    int i = blockIdx.x * 256 + threadIdx.x;   // 4-elem group index, 1,280,000 total
    int c4 = (i & 31) * 4;
    float xv[4];
    ld4h(&xh[(size_t)i * 4], xv);
    float4 sv = *reinterpret_cast<const float4*>(&sm[(size_t)i * 4]);
    float4 sc = *reinterpret_cast<const float4*>(&st[SC2 + c4]);
    float4 sh = *reinterpret_cast<const float4*>(&st[SH2 + c4]);
    float o[4];
    o[0] = sp_f(xv[0] + sv.x * sc.x + sh.x);
    o[1] = sp_f(xv[1] + sv.y * sc.y + sh.y);
    o[2] = sp_f(xv[2] + sv.z * sc.z + sh.z);
    o[3] = sp_f(xv[3] + sv.w * sc.w + sh.w);
    st4h(&xh[(size_t)i * 4], o);
}

__global__ void k_pool1(const int* __restrict__ cidx, float* __restrict__ ws) {
    int a = blockIdx.x * 256 + threadIdx.x;
    if (a < NATOMS) atomicAdd(&ws[O_STAT + SWC + cidx[a]], ws[O_W + a]);
}

__global__ void k_pool2(const int* __restrict__ cidx, float* __restrict__ ws) {
    int i = blockIdx.x * 256 + threadIdx.x;   // 5,120,000
    int a = i >> 7, c = i & 127;
    int s = cidx[a];
    const __half* xh = reinterpret_cast<const __half*>(ws + O_X);
    float coef = ws[O_W + a] / ws[O_STAT + SWC + s];
    atomicAdd(&ws[O_CRYS + (size_t)s * 128 + c], coef * __half2float(xh[(size_t)i]));
}

__global__ __launch_bounds__(256) void k_head(const float* __restrict__ fc1W,
        const float* __restrict__ fc1b, const float* __restrict__ fc2W,
        const float* __restrict__ fc2b, const float* __restrict__ outW,
        const float* __restrict__ outb, const float* __restrict__ ws,
        float* __restrict__ out) {
    __shared__ float spx[128], h1[256], h2[256], rr[4];
    int b = blockIdx.x, t = threadIdx.x;
    if (t < 128) spx[t] = sp_f(ws[O_CRYS + (size_t)b * 128 + t]);
    __syncthreads();
    float acc = fc1b[t];
    for (int k = 0; k < 128; k++) acc += spx[k] * fc1W[k * 256 + t];
    h1[t] = sp_f(acc);
    __syncthreads();
    acc = fc2b[t];
    for (int k = 0; k < 256; k++) acc += h1[k] * fc2W[k * 256 + t];
    h2[t] = sp_f(acc);
    __syncthreads();
    float p = h2[t] * outW[t];
    for (int off = 32; off > 0; off >>= 1) p += __shfl_down(p, off, 64);
    if ((t & 63) == 0) rr[t >> 6] = p;
    __syncthreads();
    if (t == 0) out[b] = rr[0] + rr[1] + rr[2] + rr[3] + outb[0];
}

extern "C" void kernel_launch(void* const* d_in, const int* in_sizes, int n_in,
                              void* d_out, int out_size, void* d_ws, size_t ws_size,
                              hipStream_t stream) {
    const float* af   = (const float*)d_in[0];
    const float* nbr  = (const float*)d_in[1];
    const int*   eidx = (const int*)d_in[2];
    const int*   cidx = (const int*)d_in[3];
    const float* embW = (const float*)d_in[4];
    const float* embB = (const float*)d_in[5];
    const float* convW= (const float*)d_in[6];
    // d_in[7] = conv_b: cancels exactly in the weighted BN that follows the conv GEMM
    const float* bn1g = (const float*)d_in[8];
    const float* bn1b = (const float*)d_in[9];
    const float* bn2g = (const float*)d_in[10];
    const float* bn2b = (const float*)d_in[11];
    const float* fc1W = (const float*)d_in[12];
    const float* fc1b = (const float*)d_in[13];
    const float* fc2W = (const float*)d_in[14];
    const float* fc2b = (const float*)d_in[15];
    const float* outW = (const float*)d_in[16];
    const float* outb = (const float*)d_in[17];
    float* ws = (float*)d_ws;
    float* out = (float*)d_out;

    // zero: SWA/SWC region + crys
    hipMemsetAsync(ws + O_STAT + 1792, 0, (size_t)(2304 + 51200) * sizeof(float), stream);
    k_embed<<<1250, 128, 0, stream>>>(af, embW, embB, ws);
    k_pool1<<<157, 256, 0, stream>>>(cidx, ws);

    // CSR build (per call; ws is re-poisoned before every timed launch)
    hipMemsetAsync(ws + O_DEG, 0, (size_t)40000 * sizeof(int), stream);
    k_hist<<<1563, 256, 0, stream>>>(eidx, ws);
    k_scan<<<1, 1024, 0, stream>>>(ws);
    hipMemsetAsync(ws + O_DEG, 0, (size_t)40000 * sizeof(int), stream);
    k_scatter<<<1563, 256, 0, stream>>>(eidx, ws);

    for (int i = 0; i < 3; i++) {
        hipMemsetAsync(ws + O_SUM, 0, (size_t)5120000 * sizeof(float), stream);
        hipMemsetAsync(ws + O_STAT, 0, (size_t)772 * sizeof(float), stream);
        const float* Wi = convW + (size_t)i * 297 * 256;
        k_wh<<<41, 256, 0, stream>>>(Wi, ws);
        k_xcat<<<1250, 256, 0, stream>>>(Wi, ws);
        k_edge0<<<3125, 256, 0, stream>>>(nbr, eidx, ws);
        k_fin1<<<1, 256, 0, stream>>>(bn1g + i * 256, bn1b + i * 256, ws);
        k_edge1<<<6250, 256, 0, stream>>>(nbr, eidx, ws);
        k_stats2<<<256, 256, 0, stream>>>(ws);
        k_fin2<<<1, 128, 0, stream>>>(bn2g + i * 128, bn2b + i * 128, ws);
        k_updx<<<5000, 256, 0, stream>>>(ws);
    }
    k_pool2<<<20000, 256, 0, stream>>>(cidx, ws);
    k_head<<<400, 256, 0, stream>>>(fc1W, fc1b, fc2W, fc2b, outW, outb, ws, out);
}

// Round 8
// 2008.531 us; speedup vs baseline: 2.0300x; 1.2174x over previous
//
#include <hip/hip_runtime.h>
#include <hip/hip_fp16.h>
#include <math.h>

#define NATOMS 40000
#define NEDGE  400000
#define NCRYS  400

// ---- workspace layout (float-slot offsets); high-water 18,504,512 floats = 74.0 MB ----
#define O_W    0                        // weights[40000] fp32
#define O_X    40960                    // x[40000*128] fp16 (2,560,000 slots)
#define O_XCAT 2600960                  // xcat[40000*512] fp16 (10,240,000 slots)
#define O_SUM  12840960                 // summed[40000*128] fp32
#define O_STAT 17960960                 // stats block [4096]
#define O_CRYS 17965056                 // crys[400*128] fp32
#define O_WH   18016256                 // We fragment-packed fp16 [16384 halves] (8192 slots)
#define O_PTR  18024448                 // CSR row ptr [40001] int (pad to 40064)
#define O_DEG  18064512                 // degree/cursor [40000] int
#define O_EORD 18104512                 // edge order [400000] int
// stat indices (within O_STAT)
#define S1SUM 0      // [0,256)
#define S1SQ  256    // [256,512)
#define S2SUM 512    // [512,640)
#define S2SQ  640    // [640,768)
#define SWE   768
// per-conv zero region = [0, 772)
#define SC1   1024   // [1024,1280)
#define SH1   1280   // [1280,1536)
#define SC2   1536   // [1536,1664)
#define SH2   1664   // [1664,1792)
#define SWA   1792
#define SWC   1800   // [1800,2200)

typedef _Float16 f16x8 __attribute__((ext_vector_type(8)));
typedef float f32x4 __attribute__((ext_vector_type(4)));

__device__ __forceinline__ float sp_f(float v) {
    return fmaxf(v, 0.f) + log1pf(expf(-fabsf(v)));
}
__device__ __forceinline__ float sig_f(float v) {
    return 1.f / (1.f + expf(-v));
}
__device__ __forceinline__ unsigned pack_h2(float a, float b) {
    __half2 h = __floats2half2_rn(a, b);
    return *reinterpret_cast<unsigned*>(&h);
}
__device__ __forceinline__ void ld4h(const __half* p, float* o) {
    int2 r = *reinterpret_cast<const int2*>(p);
    __half2 h0 = *reinterpret_cast<const __half2*>(&r.x);
    __half2 h1 = *reinterpret_cast<const __half2*>(&r.y);
    float2 f0 = __half22float2(h0), f1 = __half22float2(h1);
    o[0] = f0.x; o[1] = f0.y; o[2] = f1.x; o[3] = f1.y;
}
__device__ __forceinline__ void st4h(__half* p, const float* v) {
    uint2 pk;
    pk.x = pack_h2(v[0], v[1]); pk.y = pack_h2(v[2], v[3]);
    *reinterpret_cast<uint2*>(p) = pk;
}

// ---- embedding: weights[a]=af[a][0]; x = af[:,1:] @ embW + embB (x stored fp16) ----
__global__ __launch_bounds__(128) void k_embed(const float* __restrict__ af,
        const float* __restrict__ embW, const float* __restrict__ embB,
        float* __restrict__ ws) {
    __shared__ float at[93 * 36];   // transposed: at[k*36+m], 32 atoms/block
    int a0 = blockIdx.x * 32;
    int tid = threadIdx.x;
    for (int p = tid; p < 32 * 93; p += 128) {
        int m = p / 93, k = p - m * 93;
        at[k * 36 + m] = af[(size_t)a0 * 93 + p];
    }
    __syncthreads();
    int cq = tid & 31;   // cols cq*4..+3
    int ag = tid >> 5;   // atoms ag*8..+7
    float acc[8][4];
    float4 bb = *reinterpret_cast<const float4*>(&embB[cq * 4]);
    #pragma unroll
    for (int m = 0; m < 8; m++) { acc[m][0] = bb.x; acc[m][1] = bb.y; acc[m][2] = bb.z; acc[m][3] = bb.w; }
    for (int k = 0; k < 92; k++) {
        float4 wv = *reinterpret_cast<const float4*>(&embW[k * 128 + cq * 4]);
        const float* arow = &at[(k + 1) * 36 + ag * 8];
        #pragma unroll
        for (int m = 0; m < 8; m++) {
            float av = arow[m];
            acc[m][0] += av * wv.x; acc[m][1] += av * wv.y;
            acc[m][2] += av * wv.z; acc[m][3] += av * wv.w;
        }
    }
    __half* xh = reinterpret_cast<__half*>(ws + O_X);
    #pragma unroll
    for (int m = 0; m < 8; m++) {
        int a = a0 + ag * 8 + m;
        st4h(&xh[(size_t)a * 128 + cq * 4], acc[m]);
    }
    if (tid < 32) ws[O_W + a0 + tid] = at[0 * 36 + tid];
    if (tid == 0) {
        float s = 0.f;
        for (int m = 0; m < 32; m++) s += at[0 * 36 + m];
        atomicAdd(&ws[O_STAT + SWA], s);
    }
}

// ---- We (rows 256..296 of conv W) -> fragment-packed fp16 for MFMA B-operand ----
// frag f = t*2+ks (t=n-tile 0..15, ks=k-step 0..1); lane l; reg rg 0..7
// value = We[k][c], k = ks*32 + (l>>4)*8 + rg (0 if k>=41), c = t*16 + (l&15)
__global__ void k_wh(const float* __restrict__ Wi, float* __restrict__ ws) {
    int idx = blockIdx.x * 256 + threadIdx.x;   // 16384 halves
    if (idx >= 16384) return;
    __half* WT = reinterpret_cast<__half*>(ws + O_WH);
    int f = idx >> 9, l = (idx >> 3) & 63, rg = idx & 7;
    int t = f >> 1, s = f & 1;
    int k = s * 32 + (l >> 4) * 8 + rg;
    int c = t * 16 + (l & 15);
    float v = (k < 41) ? Wi[(256 + k) * 256 + c] : 0.f;
    WT[idx] = __float2half(v);
}

// ---- CSR build: hist -> scan -> scatter (destination = i0) ----
__global__ void k_hist(const int* __restrict__ eidx, float* __restrict__ ws) {
    int e = blockIdx.x * 256 + threadIdx.x;
    int* deg = (int*)(ws + O_DEG);
    if (e < NEDGE) atomicAdd(&deg[eidx[(size_t)e * 2]], 1);
}

__global__ __launch_bounds__(1024) void k_scan(float* __restrict__ ws) {
    const int* deg = (const int*)(ws + O_DEG);
    int* ptr = (int*)(ws + O_PTR);
    __shared__ int buf[1024];
    __shared__ int carry;
    int t = threadIdx.x;
    if (t == 0) carry = 0;
    __syncthreads();
    for (int c = 0; c < 40; c++) {
        int i = c * 1024 + t;
        int v = (i < NATOMS) ? deg[i] : 0;
        buf[t] = v;
        __syncthreads();
        for (int off = 1; off < 1024; off <<= 1) {
            int u = (t >= off) ? buf[t - off] : 0;
            __syncthreads();
            buf[t] += u;
            __syncthreads();
        }
        int inc = buf[t];
        if (i < NATOMS) ptr[i] = carry + inc - v;   // exclusive scan
        __syncthreads();
        if (t == 1023) carry += inc;
        __syncthreads();
    }
    if (t == 0) ptr[NATOMS] = carry;
}

__global__ void k_scatter(const int* __restrict__ eidx, float* __restrict__ ws) {
    int e = blockIdx.x * 256 + threadIdx.x;
    if (e >= NEDGE) return;
    const int* ptr = (const int*)(ws + O_PTR);
    int* cur = (int*)(ws + O_DEG);            // re-zeroed before this kernel
    int* eord = (int*)(ws + O_EORD);
    int i0 = eidx[(size_t)e * 2];
    int pos = ptr[i0] + atomicAdd(&cur[i0], 1);
    eord[pos] = e;
}

// ---- xcat = x @ [Wa | Wb]  -> fp16 (per conv) ----
__global__ __launch_bounds__(256) void k_xcat(const float* __restrict__ Wi,
        float* __restrict__ ws) {
    __shared__ float xt[128 * 36];   // xt[k*36+m], 32 atoms
    const __half* xh = reinterpret_cast<const __half*>(ws + O_X);
    __half* xcp = reinterpret_cast<__half*>(ws + O_XCAT);
    int a0 = blockIdx.x * 32;
    int tid = threadIdx.x;
    for (int p = tid * 4; p < 32 * 128; p += 1024) {
        float v4[4];
        ld4h(&xh[(size_t)a0 * 128 + p], v4);
        int m = p >> 7, k = p & 127;
        xt[k * 36 + m] = v4[0]; xt[(k + 1) * 36 + m] = v4[1];
        xt[(k + 2) * 36 + m] = v4[2]; xt[(k + 3) * 36 + m] = v4[3];
    }
    __syncthreads();
    int cq = tid & 63, ag = tid >> 6;
    int hb = cq >> 5;            // 0: xa (W rows 0..127), 1: xb (W rows 128..255)
    int c0 = (cq & 31) * 8;      // col within half
    const float* Wp = Wi + (size_t)hb * 128 * 256;
    float acc[8][8];
    #pragma unroll
    for (int m = 0; m < 8; m++)
        #pragma unroll
        for (int j = 0; j < 8; j++) acc[m][j] = 0.f;
    for (int k = 0; k < 128; k++) {
        float4 w0 = *reinterpret_cast<const float4*>(&Wp[k * 256 + c0]);
        float4 w1 = *reinterpret_cast<const float4*>(&Wp[k * 256 + c0 + 4]);
        const float* xr = &xt[k * 36 + ag * 8];
        #pragma unroll
        for (int m = 0; m < 8; m++) {
            float xv = xr[m];
            acc[m][0] += xv * w0.x; acc[m][1] += xv * w0.y;
            acc[m][2] += xv * w0.z; acc[m][3] += xv * w0.w;
            acc[m][4] += xv * w1.x; acc[m][5] += xv * w1.y;
            acc[m][6] += xv * w1.z; acc[m][7] += xv * w1.w;
        }
    }
    #pragma unroll
    for (int m = 0; m < 8; m++) {
        int a = a0 + ag * 8 + m;
        uint4 pk;
        pk.x = pack_h2(acc[m][0], acc[m][1]);
        pk.y = pack_h2(acc[m][2], acc[m][3]);
        pk.z = pack_h2(acc[m][4], acc[m][5]);
        pk.w = pack_h2(acc[m][6], acc[m][7]);
        *reinterpret_cast<uint4*>(&xcp[(size_t)a * 512 + hb * 256 + c0]) = pk;
    }
}

// ---- MFMA edge pass: G[64][256] = E[64][64pad] @ We ; MODE 0 stats, MODE 1 msg+scatter ----
// Per block: 64 sorted edges (eord). 4 waves; wave w owns n-tiles {w, w+4, w+8, w+12}.
// A-frag: lane row = l&15, k = ks*32 + (l>>4)*8 + reg. C: col = l&15, row = (l>>4)*4 + reg.
// Edge jj (sorted) stored at E-row r = ((jj&15)>>2)*16 + (jj>>4)*4 + (jj&3) so that
// lane quad-group q owns 16 CONSECUTIVE sorted edges jj = q*16.. (run-length scatter).
template<int MODE>
__global__ __launch_bounds__(256) void k_edge(const float* __restrict__ nbr,
        const int* __restrict__ eidx, float* __restrict__ ws) {
    __shared__ __align__(16) __half Eh[64 * 72];   // rows padded to 72 halves (144B)
    __shared__ int el[64], i0l[64], i1l[64];
    __shared__ float wl[64];
    float* st = ws + O_STAT;
    const __half* xch = reinterpret_cast<const __half*>(ws + O_XCAT);
    const __half* WT = reinterpret_cast<const __half*>(ws + O_WH);
    const int* eord = (const int*)(ws + O_EORD);
    int tid = threadIdx.x;
    int w = tid >> 6;            // wave 0..3
    int l = tid & 63;            // lane
    int l16 = l & 15, q = l >> 4;
    int e0 = blockIdx.x * 64;

    if (tid < 64) {
        int e = eord[e0 + tid];
        el[tid] = e;
        i0l[tid] = eidx[(size_t)e * 2];
        i1l[tid] = eidx[(size_t)e * 2 + 1];
    }
    __syncthreads();
    // stage E rows (fp16, zero-pad k=41..63) + wl
    for (int p = tid; p < 4096; p += 256) {
        int jj = p >> 6, k = p & 63;
        int r = ((jj & 15) >> 2) * 16 + (jj >> 4) * 4 + (jj & 3);
        float v = 0.f;
        if (k < 42) v = nbr[(size_t)el[jj] * 42 + k];
        Eh[r * 72 + k] = __float2half(k < 41 ? v : 0.f);
        if (k == 41) wl[jj] = v;
    }
    __syncthreads();

    f32x4 acc[4][4];   // [strip s4][tile tt]
    #pragma unroll
    for (int a = 0; a < 4; a++)
        #pragma unroll
        for (int b = 0; b < 4; b++) acc[a][b] = (f32x4){0.f, 0.f, 0.f, 0.f};

    #pragma unroll
    for (int ks = 0; ks < 2; ks++) {
        f16x8 bf[4];
        #pragma unroll
        for (int tt = 0; tt < 4; tt++) {
            int t = w + tt * 4;
            bf[tt] = *reinterpret_cast<const f16x8*>(WT + (size_t)((t * 2 + ks) * 512 + l * 8));
        }
        #pragma unroll
        for (int s4 = 0; s4 < 4; s4++) {
            f16x8 af = *reinterpret_cast<const f16x8*>(&Eh[(s4 * 16 + l16) * 72 + ks * 32 + q * 8]);
            #pragma unroll
            for (int tt = 0; tt < 4; tt++)
                acc[s4][tt] = __builtin_amdgcn_mfma_f32_16x16x32_f16(af, bf[tt], acc[s4][tt], 0, 0, 0);
        }
    }
    // lane's cols: c[tt] = w*16 + l16 + tt*64  (tt 0,1 filter; 2,3 core partners)
    if (MODE == 0) {
        float sS[4] = {0, 0, 0, 0}, sQ[4] = {0, 0, 0, 0};
        #pragma unroll
        for (int s4 = 0; s4 < 4; s4++) {
            #pragma unroll
            for (int i = 0; i < 4; i++) {
                int jj = q * 16 + s4 * 4 + i;
                int i0 = i0l[jj], i1 = i1l[jj];
                float wv = wl[jj];
                #pragma unroll
                for (int tt = 0; tt < 4; tt++) {
                    int c = w * 16 + l16 + tt * 64;
                    float g = acc[s4][tt][i]
                            + __half2float(xch[(size_t)i0 * 512 + c])
                            + __half2float(xch[(size_t)i1 * 512 + 256 + c]);
                    float t1 = wv * g;
                    sS[tt] += t1; sQ[tt] += t1 * g;
                }
            }
        }
        #pragma unroll
        for (int tt = 0; tt < 4; tt++) {
            sS[tt] += __shfl_xor(sS[tt], 16, 64); sS[tt] += __shfl_xor(sS[tt], 32, 64);
            sQ[tt] += __shfl_xor(sQ[tt], 16, 64); sQ[tt] += __shfl_xor(sQ[tt], 32, 64);
        }
        if (q == 0) {
            #pragma unroll
            for (int tt = 0; tt < 4; tt++) {
                int c = w * 16 + l16 + tt * 64;
                atomicAdd(&st[S1SUM + c], sS[tt]);
                atomicAdd(&st[S1SQ + c], sQ[tt]);
            }
        }
        if (tid == 0) {
            float s = 0.f;
            for (int m = 0; m < 64; m++) s += wl[m];
            atomicAdd(&st[SWE], s);
        }
    } else {
        float* summed = ws + O_SUM;
        float scf[2], shf[2], scc[2], shc[2];
        #pragma unroll
        for (int p = 0; p < 2; p++) {
            int cf = w * 16 + l16 + p * 64;
            scf[p] = st[SC1 + cf];       shf[p] = st[SH1 + cf];
            scc[p] = st[SC1 + 128 + cf]; shc[p] = st[SH1 + 128 + cf];
        }
        int prev = i0l[q * 16];
        float macc[2] = {0.f, 0.f};
        #pragma unroll
        for (int s4 = 0; s4 < 4; s4++) {
            #pragma unroll
            for (int i = 0; i < 4; i++) {
                int jj = q * 16 + s4 * 4 + i;
                int i0 = i0l[jj], i1 = i1l[jj];
                float msg[2];
                #pragma unroll
                for (int p = 0; p < 2; p++) {
                    int cf = w * 16 + l16 + p * 64;
                    float gf = acc[s4][p][i]
                             + __half2float(xch[(size_t)i0 * 512 + cf])
                             + __half2float(xch[(size_t)i1 * 512 + 256 + cf]);
                    float gc = acc[s4][p + 2][i]
                             + __half2float(xch[(size_t)i0 * 512 + 128 + cf])
                             + __half2float(xch[(size_t)i1 * 512 + 384 + cf]);
                    float fn = gf * scf[p] + shf[p];
                    float cn = gc * scc[p] + shc[p];
                    msg[p] = sig_f(fn) * sp_f(cn);
                }
                if (i0 != prev) {
                    #pragma unroll
                    for (int p = 0; p < 2; p++) {
                        int cf = w * 16 + l16 + p * 64;
                        atomicAdd(&summed[(size_t)prev * 128 + cf], macc[p]);
                        macc[p] = msg[p];
                    }
                    prev = i0;
                } else {
                    macc[0] += msg[0]; macc[1] += msg[1];
                }
            }
        }
        #pragma unroll
        for (int p = 0; p < 2; p++) {
            int cf = w * 16 + l16 + p * 64;
            atomicAdd(&summed[(size_t)prev * 128 + cf], macc[p]);
        }
    }
}

__global__ void k_fin1(const float* __restrict__ bn1g, const float* __restrict__ bn1b,
        float* __restrict__ ws) {
    float* st = ws + O_STAT;
    int c = threadIdx.x;  // 256
    float sw = st[SWE];
    float mean = st[S1SUM + c] / sw;
    float var = st[S1SQ + c] / sw - mean * mean;
    float sc = bn1g[c] / sqrtf(var + 1e-5f);
    st[SC1 + c] = sc;
    st[SH1 + c] = bn1b[c] - mean * sc;
}

__global__ __launch_bounds__(256) void k_stats2(float* __restrict__ ws) {
    const float* sm = ws + O_SUM;
    const float* w = ws + O_W;
    float* st = ws + O_STAT;
    int tid = threadIdx.x;
    int c = tid & 127, r = tid >> 7;
    float s = 0.f, q = 0.f;
    for (int a = blockIdx.x * 2 + r; a < NATOMS; a += 512) {
        float wa = w[a];
        float v = sm[(size_t)a * 128 + c];
        s += wa * v; q += wa * v * v;
    }
    __shared__ float rs[256], rq[256];
    rs[tid] = s; rq[tid] = q;
    __syncthreads();
    if (r == 0) {
        atomicAdd(&st[S2SUM + c], s + rs[tid + 128]);
        atomicAdd(&st[S2SQ + c], q + rq[tid + 128]);
    }
}

__global__ void k_fin2(const float* __restrict__ bn2g, const float* __restrict__ bn2b,
        float* __restrict__ ws) {
    float* st = ws + O_STAT;
    int c = threadIdx.x;  // 128
    float sw = st[SWA];
    float mean = st[S2SUM + c] / sw;
    float var = st[S2SQ + c] / sw - mean * mean;
    float sc = bn2g[c] / sqrtf(var + 1e-5f);
    st[SC2 + c] = sc;
    st[SH2 + c] = bn2b[c] - mean * sc;
}

__global__ __launch_bounds__(256) void k_updx(float* __restrict__ ws) {
    __half* xh = reinterpret_cast<__half*>(ws + O_X);
    const float* sm = ws + O_SUM;
    const float* st = ws + O_STAT;
    int i = blockIdx.x * 256 + threadIdx.x;   // 4-elem group index, 1,280,000 total
    int c4 = (i & 31) * 4;
    float xv[4];
    ld4h(&xh[(size_t)i * 4], xv);
    float4 sv = *reinterpret_cast<const float4*>(&sm[(size_t)i * 4]);
    float4 sc = *reinterpret_cast<const float4*>(&st[SC2 + c4]);
    float4 sh = *reinterpret_cast<const float4*>(&st[SH2 + c4]);
    float o[4];
    o[0] = sp_f(xv[0] + sv.x * sc.x + sh.x);
    o[1] = sp_f(xv[1] + sv.y * sc.y + sh.y);
    o[2] = sp_f(xv[2] + sv.z * sc.z + sh.z);
    o[3] = sp_f(xv[3] + sv.w * sc.w + sh.w);
    st4h(&xh[(size_t)i * 4], o);
}

__global__ void k_pool1(const int* __restrict__ cidx, float* __restrict__ ws) {
    int a = blockIdx.x * 256 + threadIdx.x;
    if (a < NATOMS) atomicAdd(&ws[O_STAT + SWC + cidx[a]], ws[O_W + a]);
}

__global__ void k_pool2(const int* __restrict__ cidx, float* __restrict__ ws) {
    int i = blockIdx.x * 256 + threadIdx.x;   // 5,120,000
    int a = i >> 7, c = i & 127;
    int s = cidx[a];
    const __half* xh = reinterpret_cast<const __half*>(ws + O_X);
    float coef = ws[O_W + a] / ws[O_STAT + SWC + s];
    atomicAdd(&ws[O_CRYS + (size_t)s * 128 + c], coef * __half2float(xh[(size_t)i]));
}

__global__ __launch_bounds__(256) void k_head(const float* __restrict__ fc1W,
        const float* __restrict__ fc1b, const float* __restrict__ fc2W,
        const float* __restrict__ fc2b, const float* __restrict__ outW,
        const float* __restrict__ outb, const float* __restrict__ ws,
        float* __restrict__ out) {
    __shared__ float spx[128], h1[256], h2[256], rr[4];
    int b = blockIdx.x, t = threadIdx.x;
    if (t < 128) spx[t] = sp_f(ws[O_CRYS + (size_t)b * 128 + t]);
    __syncthreads();
    float acc = fc1b[t];
    for (int k = 0; k < 128; k++) acc += spx[k] * fc1W[k * 256 + t];
    h1[t] = sp_f(acc);
    __syncthreads();
    acc = fc2b[t];
    for (int k = 0; k < 256; k++) acc += h1[k] * fc2W[k * 256 + t];
    h2[t] = sp_f(acc);
    __syncthreads();
    float p = h2[t] * outW[t];
    for (int off = 32; off > 0; off >>= 1) p += __shfl_down(p, off, 64);
    if ((t & 63) == 0) rr[t >> 6] = p;
    __syncthreads();
    if (t == 0) out[b] = rr[0] + rr[1] + rr[2] + rr[3] + outb[0];
}

extern "C" void kernel_launch(void* const* d_in, const int* in_sizes, int n_in,
                              void* d_out, int out_size, void* d_ws, size_t ws_size,
                              hipStream_t stream) {
    const float* af   = (const float*)d_in[0];
    const float* nbr  = (const float*)d_in[1];
    const int*   eidx = (const int*)d_in[2];
    const int*   cidx = (const int*)d_in[3];
    const float* embW = (const float*)d_in[4];
    const float* embB = (const float*)d_in[5];
    const float* convW= (const float*)d_in[6];
    // d_in[7] = conv_b: cancels exactly in the weighted BN that follows the conv GEMM
    const float* bn1g = (const float*)d_in[8];
    const float* bn1b = (const float*)d_in[9];
    const float* bn2g = (const float*)d_in[10];
    const float* bn2b = (const float*)d_in[11];
    const float* fc1W = (const float*)d_in[12];
    const float* fc1b = (const float*)d_in[13];
    const float* fc2W = (const float*)d_in[14];
    const float* fc2b = (const float*)d_in[15];
    const float* outW = (const float*)d_in[16];
    const float* outb = (const float*)d_in[17];
    float* ws = (float*)d_ws;
    float* out = (float*)d_out;

    // zero: SWA/SWC region + crys
    hipMemsetAsync(ws + O_STAT + 1792, 0, (size_t)(2304 + 51200) * sizeof(float), stream);
    k_embed<<<1250, 128, 0, stream>>>(af, embW, embB, ws);
    k_pool1<<<157, 256, 0, stream>>>(cidx, ws);

    // CSR build (per call; eidx constant across convs)
    hipMemsetAsync(ws + O_DEG, 0, (size_t)40000 * sizeof(int), stream);
    k_hist<<<1563, 256, 0, stream>>>(eidx, ws);
    k_scan<<<1, 1024, 0, stream>>>(ws);
    hipMemsetAsync(ws + O_DEG, 0, (size_t)40000 * sizeof(int), stream);
    k_scatter<<<1563, 256, 0, stream>>>(eidx, ws);

    for (int i = 0; i < 3; i++) {
        hipMemsetAsync(ws + O_SUM, 0, (size_t)5120000 * sizeof(float), stream);
        hipMemsetAsync(ws + O_STAT, 0, (size_t)772 * sizeof(float), stream);
        const float* Wi = convW + (size_t)i * 297 * 256;
        k_wh<<<64, 256, 0, stream>>>(Wi, ws);
        k_xcat<<<1250, 256, 0, stream>>>(Wi, ws);
        k_edge<0><<<6250, 256, 0, stream>>>(nbr, eidx, ws);
        k_fin1<<<1, 256, 0, stream>>>(bn1g + i * 256, bn1b + i * 256, ws);
        k_edge<1><<<6250, 256, 0, stream>>>(nbr, eidx, ws);
        k_stats2<<<256, 256, 0, stream>>>(ws);
        k_fin2<<<1, 128, 0, stream>>>(bn2g + i * 128, bn2b + i * 128, ws);
        k_updx<<<5000, 256, 0, stream>>>(ws);
    }
    k_pool2<<<20000, 256, 0, stream>>>(cidx, ws);
    k_head<<<400, 256, 0, stream>>>(fc1W, fc1b, fc2W, fc2b, outW, outb, ws, out);
}

// Round 9
// 1597.223 us; speedup vs baseline: 2.5528x; 1.2575x over previous
//
#include <hip/hip_runtime.h>
#include <hip/hip_fp16.h>
#include <math.h>

#define NATOMS 40000
#define NEDGE  400000
#define NCRYS  400

// ---- workspace layout (float-slot offsets); high-water 18,635,584 floats = 74.5 MB ----
#define O_W    0                        // weights[40000] fp32
#define O_X    40960                    // x[40000*128] fp16 (2,560,000 slots)
#define O_XCAT 2600960                  // xcat[40000*512] fp16, t-interleaved (10,240,000 slots)
#define O_SUM  12840960                 // summed[40000*128] fp32
#define O_STAT 17960960                 // stats block [4096]
#define O_CRYS 17965056                 // crys[400*128] fp32
#define O_WH   18016256                 // We fragment-packed fp16 [16384 halves] (8192 slots)
#define O_PTR  18024448                 // CSR row ptr [40001] int (pad to 40064)
#define O_DEG  18064512                 // degree/cursor [40000] int
#define O_EORD 18104512                 // edge order [400000] int
#define O_WAB  18504512                 // Wa|Wb column-permuted fp32 [2*128*256]
// stat indices (within O_STAT)
#define S1SUM 0      // [0,256)
#define S1SQ  256    // [256,512)
#define S2SUM 512    // [512,640)
#define S2SQ  640    // [640,768)
#define SWE   768
// per-conv zero region = [0, 772)
#define SC1   1024   // [1024,1280)
#define SH1   1280   // [1280,1536)
#define SC2   1536   // [1536,1664)
#define SH2   1664   // [1664,1792)
#define SWA   1792
#define SWC   1800   // [1800,2200)

typedef _Float16 f16x8 __attribute__((ext_vector_type(8)));
typedef float f32x4 __attribute__((ext_vector_type(4)));

#define LOG2E 1.4426950408889634f
#define LN2   0.6931471805599453f

__device__ __forceinline__ float fexp(float x) {
    return __builtin_amdgcn_exp2f(x * LOG2E);
}
__device__ __forceinline__ float sp_f(float v) {
    // softplus: max(v,0) + ln(1 + e^-|v|), via hw exp2/log2
    float t = __builtin_amdgcn_exp2f(-LOG2E * fabsf(v));
    return fmaxf(v, 0.f) + LN2 * __builtin_amdgcn_logf(1.f + t);
}
__device__ __forceinline__ float sig_f(float v) {
    return __builtin_amdgcn_rcpf(1.f + __builtin_amdgcn_exp2f(-LOG2E * v));
}
__device__ __forceinline__ unsigned pack_h2(float a, float b) {
    __half2 h = __floats2half2_rn(a, b);
    return *reinterpret_cast<unsigned*>(&h);
}
__device__ __forceinline__ void ld4h(const __half* p, float* o) {
    int2 r = *reinterpret_cast<const int2*>(p);
    __half2 h0 = *reinterpret_cast<const __half2*>(&r.x);
    __half2 h1 = *reinterpret_cast<const __half2*>(&r.y);
    float2 f0 = __half22float2(h0), f1 = __half22float2(h1);
    o[0] = f0.x; o[1] = f0.y; o[2] = f1.x; o[3] = f1.y;
}
__device__ __forceinline__ void st4h(__half* p, const float* v) {
    uint2 pk;
    pk.x = pack_h2(v[0], v[1]); pk.y = pack_h2(v[2], v[3]);
    *reinterpret_cast<uint2*>(p) = pk;
}

// ---- embedding: weights[a]=af[a][0]; x = af[:,1:] @ embW + embB (x stored fp16) ----
__global__ __launch_bounds__(128) void k_embed(const float* __restrict__ af,
        const float* __restrict__ embW, const float* __restrict__ embB,
        float* __restrict__ ws) {
    __shared__ float at[93 * 36];   // transposed: at[k*36+m], 32 atoms/block
    int a0 = blockIdx.x * 32;
    int tid = threadIdx.x;
    for (int p = tid; p < 32 * 93; p += 128) {
        int m = p / 93, k = p - m * 93;
        at[k * 36 + m] = af[(size_t)a0 * 93 + p];
    }
    __syncthreads();
    int cq = tid & 31;   // cols cq*4..+3
    int ag = tid >> 5;   // atoms ag*8..+7
    float acc[8][4];
    float4 bb = *reinterpret_cast<const float4*>(&embB[cq * 4]);
    #pragma unroll
    for (int m = 0; m < 8; m++) { acc[m][0] = bb.x; acc[m][1] = bb.y; acc[m][2] = bb.z; acc[m][3] = bb.w; }
    for (int k = 0; k < 92; k++) {
        float4 wv = *reinterpret_cast<const float4*>(&embW[k * 128 + cq * 4]);
        const float* arow = &at[(k + 1) * 36 + ag * 8];
        #pragma unroll
        for (int m = 0; m < 8; m++) {
            float av = arow[m];
            acc[m][0] += av * wv.x; acc[m][1] += av * wv.y;
            acc[m][2] += av * wv.z; acc[m][3] += av * wv.w;
        }
    }
    __half* xh = reinterpret_cast<__half*>(ws + O_X);
    #pragma unroll
    for (int m = 0; m < 8; m++) {
        int a = a0 + ag * 8 + m;
        st4h(&xh[(size_t)a * 128 + cq * 4], acc[m]);
    }
    if (tid < 32) ws[O_W + a0 + tid] = at[0 * 36 + tid];
    if (tid == 0) {
        float s = 0.f;
        for (int m = 0; m < 32; m++) s += at[0 * 36 + m];
        atomicAdd(&ws[O_STAT + SWA], s);
    }
}

// ---- Wa|Wb column-permute: wp[hb][k][cc*4+t] = W[hb*128+k][cc + t*64] ----
__global__ void k_wperm(const float* __restrict__ Wi, float* __restrict__ ws) {
    int i = blockIdx.x * 256 + threadIdx.x;   // 65536
    float* wp = ws + O_WAB;
    int hb = i >> 15, r = (i >> 8) & 127, p = i & 255;
    int cc = p >> 2, t = p & 3;
    wp[i] = Wi[(size_t)(hb * 128 + r) * 256 + cc + t * 64];
}

// ---- We (rows 256..296) -> fragment-packed fp16 for MFMA B-operand ----
__global__ void k_wh(const float* __restrict__ Wi, float* __restrict__ ws) {
    int idx = blockIdx.x * 256 + threadIdx.x;   // 16384 halves
    if (idx >= 16384) return;
    __half* WT = reinterpret_cast<__half*>(ws + O_WH);
    int f = idx >> 9, l = (idx >> 3) & 63, rg = idx & 7;
    int t = f >> 1, s = f & 1;
    int k = s * 32 + (l >> 4) * 8 + rg;
    int c = t * 16 + (l & 15);
    float v = (k < 41) ? Wi[(256 + k) * 256 + c] : 0.f;
    WT[idx] = __float2half(v);
}

// ---- CSR build: hist -> scan -> scatter (destination = i0) ----
__global__ void k_hist(const int* __restrict__ eidx, float* __restrict__ ws) {
    int e = blockIdx.x * 256 + threadIdx.x;
    int* deg = (int*)(ws + O_DEG);
    if (e < NEDGE) atomicAdd(&deg[eidx[(size_t)e * 2]], 1);
}

__global__ __launch_bounds__(1024) void k_scan(float* __restrict__ ws) {
    const int* deg = (const int*)(ws + O_DEG);
    int* ptr = (int*)(ws + O_PTR);
    __shared__ int buf[1024];
    __shared__ int carry;
    int t = threadIdx.x;
    if (t == 0) carry = 0;
    __syncthreads();
    for (int c = 0; c < 40; c++) {
        int i = c * 1024 + t;
        int v = (i < NATOMS) ? deg[i] : 0;
        buf[t] = v;
        __syncthreads();
        for (int off = 1; off < 1024; off <<= 1) {
            int u = (t >= off) ? buf[t - off] : 0;
            __syncthreads();
            buf[t] += u;
            __syncthreads();
        }
        int inc = buf[t];
        if (i < NATOMS) ptr[i] = carry + inc - v;   // exclusive scan
        __syncthreads();
        if (t == 1023) carry += inc;
        __syncthreads();
    }
    if (t == 0) ptr[NATOMS] = carry;
}

__global__ void k_scatter(const int* __restrict__ eidx, float* __restrict__ ws) {
    int e = blockIdx.x * 256 + threadIdx.x;
    if (e >= NEDGE) return;
    const int* ptr = (const int*)(ws + O_PTR);
    int* cur = (int*)(ws + O_DEG);            // re-zeroed before this kernel
    int* eord = (int*)(ws + O_EORD);
    int i0 = eidx[(size_t)e * 2];
    int pos = ptr[i0] + atomicAdd(&cur[i0], 1);
    eord[pos] = e;
}

// ---- xcat = x @ [Wa | Wb]  -> fp16, t-interleaved layout (per conv) ----
__global__ __launch_bounds__(256) void k_xcat(float* __restrict__ ws) {
    __shared__ float xt[128 * 36];   // xt[k*36+m], 32 atoms
    const __half* xh = reinterpret_cast<const __half*>(ws + O_X);
    __half* xcp = reinterpret_cast<__half*>(ws + O_XCAT);
    int a0 = blockIdx.x * 32;
    int tid = threadIdx.x;
    for (int p = tid * 4; p < 32 * 128; p += 1024) {
        float v4[4];
        ld4h(&xh[(size_t)a0 * 128 + p], v4);
        int m = p >> 7, k = p & 127;
        xt[k * 36 + m] = v4[0]; xt[(k + 1) * 36 + m] = v4[1];
        xt[(k + 2) * 36 + m] = v4[2]; xt[(k + 3) * 36 + m] = v4[3];
    }
    __syncthreads();
    int cq = tid & 63, ag = tid >> 6;
    int hb = cq >> 5;            // 0: xa, 1: xb
    int c0 = (cq & 31) * 8;      // permuted-position base within half
    const float* Wp = ws + O_WAB + (size_t)hb * 128 * 256;   // permuted columns
    float acc[8][8];
    #pragma unroll
    for (int m = 0; m < 8; m++)
        #pragma unroll
        for (int j = 0; j < 8; j++) acc[m][j] = 0.f;
    for (int k = 0; k < 128; k++) {
        float4 w0 = *reinterpret_cast<const float4*>(&Wp[k * 256 + c0]);
        float4 w1 = *reinterpret_cast<const float4*>(&Wp[k * 256 + c0 + 4]);
        const float* xr = &xt[k * 36 + ag * 8];
        #pragma unroll
        for (int m = 0; m < 8; m++) {
            float xv = xr[m];
            acc[m][0] += xv * w0.x; acc[m][1] += xv * w0.y;
            acc[m][2] += xv * w0.z; acc[m][3] += xv * w0.w;
            acc[m][4] += xv * w1.x; acc[m][5] += xv * w1.y;
            acc[m][6] += xv * w1.z; acc[m][7] += xv * w1.w;
        }
    }
    #pragma unroll
    for (int m = 0; m < 8; m++) {
        int a = a0 + ag * 8 + m;
        uint4 pk;
        pk.x = pack_h2(acc[m][0], acc[m][1]);
        pk.y = pack_h2(acc[m][2], acc[m][3]);
        pk.z = pack_h2(acc[m][4], acc[m][5]);
        pk.w = pack_h2(acc[m][6], acc[m][7]);
        *reinterpret_cast<uint4*>(&xcp[(size_t)a * 512 + hb * 256 + c0]) = pk;
    }
}

// ---- MFMA edge pass: G[64][256] = E[64][64pad] @ We ; MODE 0 stats, MODE 1 msg+scatter ----
// xcat is t-interleaved: xch[a*512 + s*256 + cc*4 + t] = original col cc+t*64 of part s.
// Lane (w,l16) owns cc = w*16+l16; one int2 gives the 4 tt-columns.
template<int MODE>
__global__ __launch_bounds__(256) void k_edge(const float* __restrict__ nbr,
        const int* __restrict__ eidx, float* __restrict__ ws) {
    __shared__ __align__(16) __half Eh[64 * 72];   // rows padded to 72 halves (144B)
    __shared__ int el[64], i0l[64], i1l[64];
    __shared__ float wl[64];
    float* st = ws + O_STAT;
    const __half* xch = reinterpret_cast<const __half*>(ws + O_XCAT);
    const __half* WT = reinterpret_cast<const __half*>(ws + O_WH);
    const int* eord = (const int*)(ws + O_EORD);
    int tid = threadIdx.x;
    int w = tid >> 6;            // wave 0..3
    int l = tid & 63;            // lane
    int l16 = l & 15, q = l >> 4;
    int cc = w * 16 + l16;       // this lane's base column within a 64-col group
    int e0 = blockIdx.x * 64;

    if (tid < 64) {
        int e = eord[e0 + tid];
        el[tid] = e;
        i0l[tid] = eidx[(size_t)e * 2];
        i1l[tid] = eidx[(size_t)e * 2 + 1];
    }
    // zero-fill Eh (cols 41..63 must be 0)
    for (int p = tid; p < 576; p += 256)
        reinterpret_cast<uint4*>(Eh)[p] = make_uint4(0, 0, 0, 0);
    __syncthreads();
    // stage E rows: float2 loads, half2 LDS writes
    for (int p = tid; p < 64 * 21; p += 256) {
        int jj = p / 21, s = p - jj * 21;     // k = 2s, 2s+1
        float2 v = *reinterpret_cast<const float2*>(&nbr[(size_t)el[jj] * 42 + s * 2]);
        int r = ((jj & 15) >> 2) * 16 + (jj >> 4) * 4 + (jj & 3);
        if (s == 20) {
            Eh[r * 72 + 40] = __float2half(v.x);
            if (MODE == 0) wl[jj] = v.y;
        } else {
            *reinterpret_cast<__half2*>(&Eh[r * 72 + s * 2]) = __floats2half2_rn(v.x, v.y);
        }
    }
    __syncthreads();

    f32x4 acc[4][4];   // [strip s4][tile tt]
    #pragma unroll
    for (int a = 0; a < 4; a++)
        #pragma unroll
        for (int b = 0; b < 4; b++) acc[a][b] = (f32x4){0.f, 0.f, 0.f, 0.f};

    #pragma unroll
    for (int ks = 0; ks < 2; ks++) {
        f16x8 bf[4];
        #pragma unroll
        for (int tt = 0; tt < 4; tt++) {
            int t = w + tt * 4;
            bf[tt] = *reinterpret_cast<const f16x8*>(WT + (size_t)((t * 2 + ks) * 512 + l * 8));
        }
        #pragma unroll
        for (int s4 = 0; s4 < 4; s4++) {
            f16x8 af = *reinterpret_cast<const f16x8*>(&Eh[(s4 * 16 + l16) * 72 + ks * 32 + q * 8]);
            #pragma unroll
            for (int tt = 0; tt < 4; tt++)
                acc[s4][tt] = __builtin_amdgcn_mfma_f32_16x16x32_f16(af, bf[tt], acc[s4][tt], 0, 0, 0);
        }
    }
    // tile tt covers original cols cc + tt*64 (tt 0,1: filter pair; 2,3: core pair)
    if (MODE == 0) {
        float sS[4] = {0, 0, 0, 0}, sQ[4] = {0, 0, 0, 0};
        int prev = -1;
        float xa4[4];
        #pragma unroll
        for (int s4 = 0; s4 < 4; s4++) {
            #pragma unroll
            for (int i = 0; i < 4; i++) {
                int jj = q * 16 + s4 * 4 + i;
                int i0 = i0l[jj], i1 = i1l[jj];
                if (i0 != prev) {
                    ld4h(&xch[(size_t)i0 * 512 + cc * 4], xa4);
                    prev = i0;
                }
                float xb4[4];
                ld4h(&xch[(size_t)i1 * 512 + 256 + cc * 4], xb4);
                float wv = wl[jj];
                #pragma unroll
                for (int tt = 0; tt < 4; tt++) {
                    float g = acc[s4][tt][i] + xa4[tt] + xb4[tt];
                    float t1 = wv * g;
                    sS[tt] += t1; sQ[tt] += t1 * g;
                }
            }
        }
        #pragma unroll
        for (int tt = 0; tt < 4; tt++) {
            sS[tt] += __shfl_xor(sS[tt], 16, 64); sS[tt] += __shfl_xor(sS[tt], 32, 64);
            sQ[tt] += __shfl_xor(sQ[tt], 16, 64); sQ[tt] += __shfl_xor(sQ[tt], 32, 64);
        }
        if (q == 0) {
            #pragma unroll
            for (int tt = 0; tt < 4; tt++) {
                int c = cc + tt * 64;
                atomicAdd(&st[S1SUM + c], sS[tt]);
                atomicAdd(&st[S1SQ + c], sQ[tt]);
            }
        }
        if (tid == 0) {
            float s = 0.f;
            for (int m = 0; m < 64; m++) s += wl[m];
            atomicAdd(&st[SWE], s);
        }
    } else {
        float* summed = ws + O_SUM;
        float scf[2], shf[2], scc[2], shc[2];
        #pragma unroll
        for (int p = 0; p < 2; p++) {
            int cf = cc + p * 64;
            scf[p] = st[SC1 + cf];       shf[p] = st[SH1 + cf];
            scc[p] = st[SC1 + 128 + cf]; shc[p] = st[SH1 + 128 + cf];
        }
        int prev = i0l[q * 16];
        float xa4[4];
        ld4h(&xch[(size_t)prev * 512 + cc * 4], xa4);
        float macc[2] = {0.f, 0.f};
        #pragma unroll
        for (int s4 = 0; s4 < 4; s4++) {
            #pragma unroll
            for (int i = 0; i < 4; i++) {
                int jj = q * 16 + s4 * 4 + i;
                int i0 = i0l[jj], i1 = i1l[jj];
                if (i0 != prev) {
                    int cf0 = cc, cf1 = cc + 64;
                    atomicAdd(&summed[(size_t)prev * 128 + cf0], macc[0]);
                    atomicAdd(&summed[(size_t)prev * 128 + cf1], macc[1]);
                    macc[0] = 0.f; macc[1] = 0.f;
                    prev = i0;
                    ld4h(&xch[(size_t)i0 * 512 + cc * 4], xa4);
                }
                float xb4[4];
                ld4h(&xch[(size_t)i1 * 512 + 256 + cc * 4], xb4);
                #pragma unroll
                for (int p = 0; p < 2; p++) {
                    float gf = acc[s4][p][i] + xa4[p] + xb4[p];
                    float gc = acc[s4][p + 2][i] + xa4[p + 2] + xb4[p + 2];
                    float fn = gf * scf[p] + shf[p];
                    float cn = gc * scc[p] + shc[p];
                    macc[p] += sig_f(fn) * sp_f(cn);
                }
            }
        }
        #pragma unroll
        for (int p = 0; p < 2; p++)
            atomicAdd(&summed[(size_t)prev * 128 + cc + p * 64], macc[p]);
    }
}

__global__ void k_fin1(const float* __restrict__ bn1g, const float* __restrict__ bn1b,
        float* __restrict__ ws) {
    float* st = ws + O_STAT;
    int c = threadIdx.x;  // 256
    float sw = st[SWE];
    float mean = st[S1SUM + c] / sw;
    float var = st[S1SQ + c] / sw - mean * mean;
    float sc = bn1g[c] / sqrtf(var + 1e-5f);
    st[SC1 + c] = sc;
    st[SH1 + c] = bn1b[c] - mean * sc;
}

__global__ __launch_bounds__(256) void k_stats2(float* __restrict__ ws) {
    const float* sm = ws + O_SUM;
    const float* w = ws + O_W;
    float* st = ws + O_STAT;
    int tid = threadIdx.x;
    int c = tid & 127, r = tid >> 7;
    float s = 0.f, q = 0.f;
    for (int a = blockIdx.x * 2 + r; a < NATOMS; a += 512) {
        float wa = w[a];
        float v = sm[(size_t)a * 128 + c];
        s += wa * v; q += wa * v * v;
    }
    __shared__ float rs[256], rq[256];
    rs[tid] = s; rq[tid] = q;
    __syncthreads();
    if (r == 0) {
        atomicAdd(&st[S2SUM + c], s + rs[tid + 128]);
        atomicAdd(&st[S2SQ + c], q + rq[tid + 128]);
    }
}

__global__ void k_fin2(const float* __restrict__ bn2g, const float* __restrict__ bn2b,
        float* __restrict__ ws) {
    float* st = ws + O_STAT;
    int c = threadIdx.x;  // 128
    float sw = st[SWA];
    float mean = st[S2SUM + c] / sw;
    float var = st[S2SQ + c] / sw - mean * mean;
    float sc = bn2g[c] / sqrtf(var + 1e-5f);
    st[SC2 + c] = sc;
    st[SH2 + c] = bn2b[c] - mean * sc;
}

__global__ __launch_bounds__(256) void k_updx(float* __restrict__ ws) {
    __half* xh = reinterpret_cast<__half*>(ws + O_X);
    const float* sm = ws + O_SUM;
    const float* st = ws + O_STAT;
    int i = blockIdx.x * 256 + threadIdx.x;   // 4-elem group index, 1,280,000 total
    int c4 = (i & 31) * 4;
    float xv[4];
    ld4h(&xh[(size_t)i * 4], xv);
    float4 sv = *reinterpret_cast<const float4*>(&sm[(size_t)i * 4]);
    float4 sc = *reinterpret_cast<const float4*>(&st[SC2 + c4]);
    float4 sh = *reinterpret_cast<const float4*>(&st[SH2 + c4]);
    float o[4];
    o[0] = sp_f(xv[0] + sv.x * sc.x + sh.x);
    o[1] = sp_f(xv[1] + sv.y * sc.y + sh.y);
    o[2] = sp_f(xv[2] + sv.z * sc.z + sh.z);
    o[3] = sp_f(xv[3] + sv.w * sc.w + sh.w);
    st4h(&xh[(size_t)i * 4], o);
}

__global__ void k_pool1(const int* __restrict__ cidx, float* __restrict__ ws) {
    int a = blockIdx.x * 256 + threadIdx.x;
    if (a < NATOMS) atomicAdd(&ws[O_STAT + SWC + cidx[a]], ws[O_W + a]);
}

__global__ void k_pool2(const int* __restrict__ cidx, float* __restrict__ ws) {
    int i = blockIdx.x * 256 + threadIdx.x;   // 5,120,000
    int a = i >> 7, c = i & 127;
    int s = cidx[a];
    const __half* xh = reinterpret_cast<const __half*>(ws + O_X);
    float coef = ws[O_W + a] / ws[O_STAT + SWC + s];
    atomicAdd(&ws[O_CRYS + (size_t)s * 128 + c], coef * __half2float(xh[(size_t)i]));
}

__global__ __launch_bounds__(256) void k_head(const float* __restrict__ fc1W,
        const float* __restrict__ fc1b, const float* __restrict__ fc2W,
        const float* __restrict__ fc2b, const float* __restrict__ outW,
        const float* __restrict__ outb, const float* __restrict__ ws,
        float* __restrict__ out) {
    __shared__ float spx[128], h1[256], h2[256], rr[4];
    int b = blockIdx.x, t = threadIdx.x;
    if (t < 128) spx[t] = sp_f(ws[O_CRYS + (size_t)b * 128 + t]);
    __syncthreads();
    float acc = fc1b[t];
    for (int k = 0; k < 128; k++) acc += spx[k] * fc1W[k * 256 + t];
    h1[t] = sp_f(acc);
    __syncthreads();
    acc = fc2b[t];
    for (int k = 0; k < 256; k++) acc += h1[k] * fc2W[k * 256 + t];
    h2[t] = sp_f(acc);
    __syncthreads();
    float p = h2[t] * outW[t];
    for (int off = 32; off > 0; off >>= 1) p += __shfl_down(p, off, 64);
    if ((t & 63) == 0) rr[t >> 6] = p;
    __syncthreads();
    if (t == 0) out[b] = rr[0] + rr[1] + rr[2] + rr[3] + outb[0];
}

extern "C" void kernel_launch(void* const* d_in, const int* in_sizes, int n_in,
                              void* d_out, int out_size, void* d_ws, size_t ws_size,
                              hipStream_t stream) {
    const float* af   = (const float*)d_in[0];
    const float* nbr  = (const float*)d_in[1];
    const int*   eidx = (const int*)d_in[2];
    const int*   cidx = (const int*)d_in[3];
    const float* embW = (const float*)d_in[4];
    const float* embB = (const float*)d_in[5];
    const float* convW= (const float*)d_in[6];
    // d_in[7] = conv_b: cancels exactly in the weighted BN that follows the conv GEMM
    const float* bn1g = (const float*)d_in[8];
    const float* bn1b = (const float*)d_in[9];
    const float* bn2g = (const float*)d_in[10];
    const float* bn2b = (const float*)d_in[11];
    const float* fc1W = (const float*)d_in[12];
    const float* fc1b = (const float*)d_in[13];
    const float* fc2W = (const float*)d_in[14];
    const float* fc2b = (const float*)d_in[15];
    const float* outW = (const float*)d_in[16];
    const float* outb = (const float*)d_in[17];
    float* ws = (float*)d_ws;
    float* out = (float*)d_out;

    // zero: SWA/SWC region + crys
    hipMemsetAsync(ws + O_STAT + 1792, 0, (size_t)(2304 + 51200) * sizeof(float), stream);
    k_embed<<<1250, 128, 0, stream>>>(af, embW, embB, ws);
    k_pool1<<<157, 256, 0, stream>>>(cidx, ws);

    // CSR build (per call; eidx constant across convs)
    hipMemsetAsync(ws + O_DEG, 0, (size_t)40000 * sizeof(int), stream);
    k_hist<<<1563, 256, 0, stream>>>(eidx, ws);
    k_scan<<<1, 1024, 0, stream>>>(ws);
    hipMemsetAsync(ws + O_DEG, 0, (size_t)40000 * sizeof(int), stream);
    k_scatter<<<1563, 256, 0, stream>>>(eidx, ws);

    for (int i = 0; i < 3; i++) {
        hipMemsetAsync(ws + O_SUM, 0, (size_t)5120000 * sizeof(float), stream);
        hipMemsetAsync(ws + O_STAT, 0, (size_t)772 * sizeof(float), stream);
        const float* Wi = convW + (size_t)i * 297 * 256;
        k_wperm<<<256, 256, 0, stream>>>(Wi, ws);
        k_wh<<<64, 256, 0, stream>>>(Wi, ws);
        k_xcat<<<1250, 256, 0, stream>>>(ws);
        k_edge<0><<<6250, 256, 0, stream>>>(nbr, eidx, ws);
        k_fin1<<<1, 256, 0, stream>>>(bn1g + i * 256, bn1b + i * 256, ws);
        k_edge<1><<<6250, 256, 0, stream>>>(nbr, eidx, ws);
        k_stats2<<<256, 256, 0, stream>>>(ws);
        k_fin2<<<1, 128, 0, stream>>>(bn2g + i * 128, bn2b + i * 128, ws);
        k_updx<<<5000, 256, 0, stream>>>(ws);
    }
    k_pool2<<<20000, 256, 0, stream>>>(cidx, ws);
    k_head<<<400, 256, 0, stream>>>(fc1W, fc1b, fc2W, fc2b, outW, outb, ws, out);
}

// Round 10
// 1529.290 us; speedup vs baseline: 2.6662x; 1.0444x over previous
//
#include <hip/hip_runtime.h>
#include <hip/hip_fp16.h>
#include <math.h>

#define NATOMS 40000
#define NEDGE  400000
#define NCRYS  400

// ---- workspace layout (float-slot offsets); high-water 18,635,584 floats = 74.5 MB ----
#define O_W    0                        // weights[40000] fp32
#define O_X    40960                    // x[40000*128] fp16 (2,560,000 slots)
#define O_XCAT 2600960                  // xcat[40000*512] fp16, t-interleaved (10,240,000 slots)
#define O_SUM  12840960                 // summed[40000*128] fp32
#define O_STAT 17960960                 // stats block [4096]
#define O_CRYS 17965056                 // crys[400*128] fp32
#define O_WH   18016256                 // We fragment-packed fp16 [16384 halves] (8192 slots)
#define O_PTR  18024448                 // CSR row ptr [40001] int (pad to 40064)
#define O_DEG  18064512                 // degree/cursor [40000] int
#define O_EORD 18104512                 // edge order [400000] int
#define O_WAB  18504512                 // Wa|Wb column-permuted fp32 [2*128*256]
// stat indices (within O_STAT)
#define S1SUM 0      // [0,256)
#define S1SQ  256    // [256,512)
#define S2SUM 512    // [512,640)
#define S2SQ  640    // [640,768)
#define SWE   768
// per-conv zero region = [0, 772)
#define SC1   1024   // [1024,1280)
#define SH1   1280   // [1280,1536)
#define SC2   1536   // [1536,1664)
#define SH2   1664   // [1664,1792)
#define SWA   1792
#define SWC   1800   // [1800,2200)

typedef _Float16 f16x8 __attribute__((ext_vector_type(8)));
typedef float f32x4 __attribute__((ext_vector_type(4)));

#define LOG2E 1.4426950408889634f
#define LN2   0.6931471805599453f

__device__ __forceinline__ float sp_f(float v) {
    float t = __builtin_amdgcn_exp2f(-LOG2E * fabsf(v));
    return fmaxf(v, 0.f) + LN2 * __builtin_amdgcn_logf(1.f + t);
}
__device__ __forceinline__ float sig_f(float v) {
    return __builtin_amdgcn_rcpf(1.f + __builtin_amdgcn_exp2f(-LOG2E * v));
}
__device__ __forceinline__ unsigned pack_h2(float a, float b) {
    __half2 h = __floats2half2_rn(a, b);
    return *reinterpret_cast<unsigned*>(&h);
}
__device__ __forceinline__ void ld4h(const __half* p, float* o) {
    int2 r = *reinterpret_cast<const int2*>(p);
    __half2 h0 = *reinterpret_cast<const __half2*>(&r.x);
    __half2 h1 = *reinterpret_cast<const __half2*>(&r.y);
    float2 f0 = __half22float2(h0), f1 = __half22float2(h1);
    o[0] = f0.x; o[1] = f0.y; o[2] = f1.x; o[3] = f1.y;
}
__device__ __forceinline__ void cvt4h(int2 r, float* o) {
    __half2 h0 = *reinterpret_cast<const __half2*>(&r.x);
    __half2 h1 = *reinterpret_cast<const __half2*>(&r.y);
    float2 f0 = __half22float2(h0), f1 = __half22float2(h1);
    o[0] = f0.x; o[1] = f0.y; o[2] = f1.x; o[3] = f1.y;
}
__device__ __forceinline__ void st4h(__half* p, const float* v) {
    uint2 pk;
    pk.x = pack_h2(v[0], v[1]); pk.y = pack_h2(v[2], v[3]);
    *reinterpret_cast<uint2*>(p) = pk;
}

// ---- embedding: weights[a]=af[a][0]; x = af[:,1:] @ embW + embB (x stored fp16) ----
__global__ __launch_bounds__(128) void k_embed(const float* __restrict__ af,
        const float* __restrict__ embW, const float* __restrict__ embB,
        float* __restrict__ ws) {
    __shared__ float at[93 * 36];   // transposed: at[k*36+m], 32 atoms/block
    int a0 = blockIdx.x * 32;
    int tid = threadIdx.x;
    for (int p = tid; p < 32 * 93; p += 128) {
        int m = p / 93, k = p - m * 93;
        at[k * 36 + m] = af[(size_t)a0 * 93 + p];
    }
    __syncthreads();
    int cq = tid & 31;   // cols cq*4..+3
    int ag = tid >> 5;   // atoms ag*8..+7
    float acc[8][4];
    float4 bb = *reinterpret_cast<const float4*>(&embB[cq * 4]);
    #pragma unroll
    for (int m = 0; m < 8; m++) { acc[m][0] = bb.x; acc[m][1] = bb.y; acc[m][2] = bb.z; acc[m][3] = bb.w; }
    for (int k = 0; k < 92; k++) {
        float4 wv = *reinterpret_cast<const float4*>(&embW[k * 128 + cq * 4]);
        const float* arow = &at[(k + 1) * 36 + ag * 8];
        #pragma unroll
        for (int m = 0; m < 8; m++) {
            float av = arow[m];
            acc[m][0] += av * wv.x; acc[m][1] += av * wv.y;
            acc[m][2] += av * wv.z; acc[m][3] += av * wv.w;
        }
    }
    __half* xh = reinterpret_cast<__half*>(ws + O_X);
    #pragma unroll
    for (int m = 0; m < 8; m++) {
        int a = a0 + ag * 8 + m;
        st4h(&xh[(size_t)a * 128 + cq * 4], acc[m]);
    }
    if (tid < 32) ws[O_W + a0 + tid] = at[0 * 36 + tid];
    if (tid == 0) {
        float s = 0.f;
        for (int m = 0; m < 32; m++) s += at[0 * 36 + m];
        atomicAdd(&ws[O_STAT + SWA], s);
    }
}

// ---- Wa|Wb column-permute: wp[hb][k][cc*4+t] = W[hb*128+k][cc + t*64] ----
__global__ void k_wperm(const float* __restrict__ Wi, float* __restrict__ ws) {
    int i = blockIdx.x * 256 + threadIdx.x;   // 65536
    float* wp = ws + O_WAB;
    int hb = i >> 15, r = (i >> 8) & 127, p = i & 255;
    int cc = p >> 2, t = p & 3;
    wp[i] = Wi[(size_t)(hb * 128 + r) * 256 + cc + t * 64];
}

// ---- We (rows 256..296) -> fragment-packed fp16 for MFMA B-operand ----
__global__ void k_wh(const float* __restrict__ Wi, float* __restrict__ ws) {
    int idx = blockIdx.x * 256 + threadIdx.x;   // 16384 halves
    if (idx >= 16384) return;
    __half* WT = reinterpret_cast<__half*>(ws + O_WH);
    int f = idx >> 9, l = (idx >> 3) & 63, rg = idx & 7;
    int t = f >> 1, s = f & 1;
    int k = s * 32 + (l >> 4) * 8 + rg;
    int c = t * 16 + (l & 15);
    float v = (k < 41) ? Wi[(256 + k) * 256 + c] : 0.f;
    WT[idx] = __float2half(v);
}

// ---- CSR build: hist -> scan -> scatter (destination = i0) ----
__global__ void k_hist(const int* __restrict__ eidx, float* __restrict__ ws) {
    int e = blockIdx.x * 256 + threadIdx.x;
    int* deg = (int*)(ws + O_DEG);
    if (e < NEDGE) atomicAdd(&deg[eidx[(size_t)e * 2]], 1);
}

__global__ __launch_bounds__(1024) void k_scan(float* __restrict__ ws) {
    const int* deg = (const int*)(ws + O_DEG);
    int* ptr = (int*)(ws + O_PTR);
    __shared__ int buf[1024];
    __shared__ int carry;
    int t = threadIdx.x;
    if (t == 0) carry = 0;
    __syncthreads();
    for (int c = 0; c < 40; c++) {
        int i = c * 1024 + t;
        int v = (i < NATOMS) ? deg[i] : 0;
        buf[t] = v;
        __syncthreads();
        for (int off = 1; off < 1024; off <<= 1) {
            int u = (t >= off) ? buf[t - off] : 0;
            __syncthreads();
            buf[t] += u;
            __syncthreads();
        }
        int inc = buf[t];
        if (i < NATOMS) ptr[i] = carry + inc - v;   // exclusive scan
        __syncthreads();
        if (t == 1023) carry += inc;
        __syncthreads();
    }
    if (t == 0) ptr[NATOMS] = carry;
}

__global__ void k_scatter(const int* __restrict__ eidx, float* __restrict__ ws) {
    int e = blockIdx.x * 256 + threadIdx.x;
    if (e >= NEDGE) return;
    const int* ptr = (const int*)(ws + O_PTR);
    int* cur = (int*)(ws + O_DEG);            // re-zeroed before this kernel
    int* eord = (int*)(ws + O_EORD);
    int i0 = eidx[(size_t)e * 2];
    int pos = ptr[i0] + atomicAdd(&cur[i0], 1);
    eord[pos] = e;
}

// ---- xcat = x @ [Wa | Wb]  -> fp16, t-interleaved layout (per conv) ----
__global__ __launch_bounds__(256) void k_xcat(float* __restrict__ ws) {
    __shared__ float xt[128 * 36];   // xt[k*36+m], 32 atoms
    const __half* xh = reinterpret_cast<const __half*>(ws + O_X);
    __half* xcp = reinterpret_cast<__half*>(ws + O_XCAT);
    int a0 = blockIdx.x * 32;
    int tid = threadIdx.x;
    for (int p = tid * 4; p < 32 * 128; p += 1024) {
        float v4[4];
        ld4h(&xh[(size_t)a0 * 128 + p], v4);
        int m = p >> 7, k = p & 127;
        xt[k * 36 + m] = v4[0]; xt[(k + 1) * 36 + m] = v4[1];
        xt[(k + 2) * 36 + m] = v4[2]; xt[(k + 3) * 36 + m] = v4[3];
    }
    __syncthreads();
    int cq = tid & 63, ag = tid >> 6;
    int hb = cq >> 5;            // 0: xa, 1: xb
    int c0 = (cq & 31) * 8;      // permuted-position base within half
    const float* Wp = ws + O_WAB + (size_t)hb * 128 * 256;   // permuted columns
    float acc[8][8];
    #pragma unroll
    for (int m = 0; m < 8; m++)
        #pragma unroll
        for (int j = 0; j < 8; j++) acc[m][j] = 0.f;
    for (int k = 0; k < 128; k++) {
        float4 w0 = *reinterpret_cast<const float4*>(&Wp[k * 256 + c0]);
        float4 w1 = *reinterpret_cast<const float4*>(&Wp[k * 256 + c0 + 4]);
        const float* xr = &xt[k * 36 + ag * 8];
        #pragma unroll
        for (int m = 0; m < 8; m++) {
            float xv = xr[m];
            acc[m][0] += xv * w0.x; acc[m][1] += xv * w0.y;
            acc[m][2] += xv * w0.z; acc[m][3] += xv * w0.w;
            acc[m][4] += xv * w1.x; acc[m][5] += xv * w1.y;
            acc[m][6] += xv * w1.z; acc[m][7] += xv * w1.w;
        }
    }
    #pragma unroll
    for (int m = 0; m < 8; m++) {
        int a = a0 + ag * 8 + m;
        uint4 pk;
        pk.x = pack_h2(acc[m][0], acc[m][1]);
        pk.y = pack_h2(acc[m][2], acc[m][3]);
        pk.z = pack_h2(acc[m][4], acc[m][5]);
        pk.w = pack_h2(acc[m][6], acc[m][7]);
        *reinterpret_cast<uint4*>(&xcp[(size_t)a * 512 + hb * 256 + c0]) = pk;
    }
}

// ---- MFMA edge pass: G[64][256] = E[64][64pad] @ We ; MODE 0 stats, MODE 1 msg+scatter ----
// xcat is t-interleaved: xch[a*512 + s*256 + cc*4 + t] = original col cc+t*64 of part s.
// Lane (w,l16) owns cc = w*16+l16; one int2 gives the 4 tt-columns.
// All 16 xb gathers are PRELOADED into registers before compute (MLP batching).
template<int MODE>
__global__ __launch_bounds__(256, 2) void k_edge(const float* __restrict__ nbr,
        const int* __restrict__ eidx, float* __restrict__ ws) {
    __shared__ __align__(16) __half Eh[64 * 72];   // rows padded to 72 halves (144B)
    __shared__ int el[64], i0l[64], i1l[64];
    __shared__ float wl[64];
    float* st = ws + O_STAT;
    const __half* xch = reinterpret_cast<const __half*>(ws + O_XCAT);
    const __half* WT = reinterpret_cast<const __half*>(ws + O_WH);
    const int* eord = (const int*)(ws + O_EORD);
    int tid = threadIdx.x;
    int w = tid >> 6;            // wave 0..3
    int l = tid & 63;            // lane
    int l16 = l & 15, q = l >> 4;
    int cc = w * 16 + l16;       // this lane's base column within a 64-col group
    int e0 = blockIdx.x * 64;

    if (tid < 64) {
        int e = eord[e0 + tid];
        el[tid] = e;
        i0l[tid] = eidx[(size_t)e * 2];
        i1l[tid] = eidx[(size_t)e * 2 + 1];
    }
    // zero-fill Eh (cols 41..63 must be 0)
    for (int p = tid; p < 576; p += 256)
        reinterpret_cast<uint4*>(Eh)[p] = make_uint4(0, 0, 0, 0);
    __syncthreads();
    // stage E rows: float2 loads, half2 LDS writes
    for (int p = tid; p < 64 * 21; p += 256) {
        int jj = p / 21, s = p - jj * 21;     // k = 2s, 2s+1
        float2 v = *reinterpret_cast<const float2*>(&nbr[(size_t)el[jj] * 42 + s * 2]);
        int r = ((jj & 15) >> 2) * 16 + (jj >> 4) * 4 + (jj & 3);
        if (s == 20) {
            Eh[r * 72 + 40] = __float2half(v.x);
            if (MODE == 0) wl[jj] = v.y;
        } else {
            *reinterpret_cast<__half2*>(&Eh[r * 72 + s * 2]) = __floats2half2_rn(v.x, v.y);
        }
    }
    __syncthreads();

    // ---- batch-issue all 16 xb gathers (raw int2; convert lazily) ----
    int2 xbr[16];
    #pragma unroll
    for (int m16 = 0; m16 < 16; m16++) {
        int i1 = i1l[q * 16 + m16];
        xbr[m16] = *reinterpret_cast<const int2*>(&xch[(size_t)i1 * 512 + 256 + cc * 4]);
    }

    f32x4 acc[4][4];   // [strip s4][tile tt]
    #pragma unroll
    for (int a = 0; a < 4; a++)
        #pragma unroll
        for (int b = 0; b < 4; b++) acc[a][b] = (f32x4){0.f, 0.f, 0.f, 0.f};

    #pragma unroll
    for (int ks = 0; ks < 2; ks++) {
        f16x8 bf[4];
        #pragma unroll
        for (int tt = 0; tt < 4; tt++) {
            int t = w + tt * 4;
            bf[tt] = *reinterpret_cast<const f16x8*>(WT + (size_t)((t * 2 + ks) * 512 + l * 8));
        }
        #pragma unroll
        for (int s4 = 0; s4 < 4; s4++) {
            f16x8 af = *reinterpret_cast<const f16x8*>(&Eh[(s4 * 16 + l16) * 72 + ks * 32 + q * 8]);
            #pragma unroll
            for (int tt = 0; tt < 4; tt++)
                acc[s4][tt] = __builtin_amdgcn_mfma_f32_16x16x32_f16(af, bf[tt], acc[s4][tt], 0, 0, 0);
        }
    }
    // tile tt covers original cols cc + tt*64 (tt 0,1: filter pair; 2,3: core pair)
    if (MODE == 0) {
        float sS[4] = {0, 0, 0, 0}, sQ[4] = {0, 0, 0, 0};
        int prev = -1;
        float xa4[4];
        #pragma unroll
        for (int m16 = 0; m16 < 16; m16++) {
            int jj = q * 16 + m16;
            int i0 = i0l[jj];
            if (i0 != prev) {
                ld4h(&xch[(size_t)i0 * 512 + cc * 4], xa4);
                prev = i0;
            }
            float xb4[4];
            cvt4h(xbr[m16], xb4);
            float wv = wl[jj];
            #pragma unroll
            for (int tt = 0; tt < 4; tt++) {
                float g = acc[m16 >> 2][tt][m16 & 3] + xa4[tt] + xb4[tt];
                float t1 = wv * g;
                sS[tt] += t1; sQ[tt] += t1 * g;
            }
        }
        #pragma unroll
        for (int tt = 0; tt < 4; tt++) {
            sS[tt] += __shfl_xor(sS[tt], 16, 64); sS[tt] += __shfl_xor(sS[tt], 32, 64);
            sQ[tt] += __shfl_xor(sQ[tt], 16, 64); sQ[tt] += __shfl_xor(sQ[tt], 32, 64);
        }
        if (q == 0) {
            #pragma unroll
            for (int tt = 0; tt < 4; tt++) {
                int c = cc + tt * 64;
                atomicAdd(&st[S1SUM + c], sS[tt]);
                atomicAdd(&st[S1SQ + c], sQ[tt]);
            }
        }
        if (tid == 0) {
            float s = 0.f;
            for (int m = 0; m < 64; m++) s += wl[m];
            atomicAdd(&st[SWE], s);
        }
    } else {
        float* summed = ws + O_SUM;
        float scf[2], shf[2], scc[2], shc[2];
        #pragma unroll
        for (int p = 0; p < 2; p++) {
            int cf = cc + p * 64;
            scf[p] = st[SC1 + cf];       shf[p] = st[SH1 + cf];
            scc[p] = st[SC1 + 128 + cf]; shc[p] = st[SH1 + 128 + cf];
        }
        int prev = i0l[q * 16];
        float xa4[4];
        ld4h(&xch[(size_t)prev * 512 + cc * 4], xa4);
        float macc[2] = {0.f, 0.f};
        #pragma unroll
        for (int m16 = 0; m16 < 16; m16++) {
            int jj = q * 16 + m16;
            int i0 = i0l[jj];
            if (i0 != prev) {
                atomicAdd(&summed[(size_t)prev * 128 + cc], macc[0]);
                atomicAdd(&summed[(size_t)prev * 128 + cc + 64], macc[1]);
                macc[0] = 0.f; macc[1] = 0.f;
                prev = i0;
                ld4h(&xch[(size_t)i0 * 512 + cc * 4], xa4);
            }
            float xb4[4];
            cvt4h(xbr[m16], xb4);
            #pragma unroll
            for (int p = 0; p < 2; p++) {
                float gf = acc[m16 >> 2][p][m16 & 3] + xa4[p] + xb4[p];
                float gc = acc[m16 >> 2][p + 2][m16 & 3] + xa4[p + 2] + xb4[p + 2];
                float fn = gf * scf[p] + shf[p];
                float cn = gc * scc[p] + shc[p];
                macc[p] += sig_f(fn) * sp_f(cn);
            }
        }
        #pragma unroll
        for (int p = 0; p < 2; p++)
            atomicAdd(&summed[(size_t)prev * 128 + cc + p * 64], macc[p]);
    }
}

__global__ void k_fin1(const float* __restrict__ bn1g, const float* __restrict__ bn1b,
        float* __restrict__ ws) {
    float* st = ws + O_STAT;
    int c = threadIdx.x;  // 256
    float sw = st[SWE];
    float mean = st[S1SUM + c] / sw;
    float var = st[S1SQ + c] / sw - mean * mean;
    float sc = bn1g[c] / sqrtf(var + 1e-5f);
    st[SC1 + c] = sc;
    st[SH1 + c] = bn1b[c] - mean * sc;
}

__global__ __launch_bounds__(256) void k_stats2(float* __restrict__ ws) {
    const float* sm = ws + O_SUM;
    const float* w = ws + O_W;
    float* st = ws + O_STAT;
    int tid = threadIdx.x;
    int c = tid & 127, r = tid >> 7;
    float s = 0.f, q = 0.f;
    for (int a = blockIdx.x * 2 + r; a < NATOMS; a += 512) {
        float wa = w[a];
        float v = sm[(size_t)a * 128 + c];
        s += wa * v; q += wa * v * v;
    }
    __shared__ float rs[256], rq[256];
    rs[tid] = s; rq[tid] = q;
    __syncthreads();
    if (r == 0) {
        atomicAdd(&st[S2SUM + c], s + rs[tid + 128]);
        atomicAdd(&st[S2SQ + c], q + rq[tid + 128]);
    }
}

__global__ void k_fin2(const float* __restrict__ bn2g, const float* __restrict__ bn2b,
        float* __restrict__ ws) {
    float* st = ws + O_STAT;
    int c = threadIdx.x;  // 128
    float sw = st[SWA];
    float mean = st[S2SUM + c] / sw;
    float var = st[S2SQ + c] / sw - mean * mean;
    float sc = bn2g[c] / sqrtf(var + 1e-5f);
    st[SC2 + c] = sc;
    st[SH2 + c] = bn2b[c] - mean * sc;
}

__global__ __launch_bounds__(256) void k_updx(float* __restrict__ ws) {
    __half* xh = reinterpret_cast<__half*>(ws + O_X);
    const float* sm = ws + O_SUM;
    const float* st = ws + O_STAT;
    int i = blockIdx.x * 256 + threadIdx.x;   // 4-elem group index, 1,280,000 total
    int c4 = (i & 31) * 4;
    float xv[4];
    ld4h(&xh[(size_t)i * 4], xv);
    float4 sv = *reinterpret_cast<const float4*>(&sm[(size_t)i * 4]);
    float4 sc = *reinterpret_cast<const float4*>(&st[SC2 + c4]);
    float4 sh = *reinterpret_cast<const float4*>(&st[SH2 + c4]);
    float o[4];
    o[0] = sp_f(xv[0] + sv.x * sc.x + sh.x);
    o[1] = sp_f(xv[1] + sv.y * sc.y + sh.y);
    o[2] = sp_f(xv[2] + sv.z * sc.z + sh.z);
    o[3] = sp_f(xv[3] + sv.w * sc.w + sh.w);
    st4h(&xh[(size_t)i * 4], o);
}

__global__ void k_pool1(const int* __restrict__ cidx, float* __restrict__ ws) {
    int a = blockIdx.x * 256 + threadIdx.x;
    if (a < NATOMS) atomicAdd(&ws[O_STAT + SWC + cidx[a]], ws[O_W + a]);
}

__global__ void k_pool2(const int* __restrict__ cidx, float* __restrict__ ws) {
    int i = blockIdx.x * 256 + threadIdx.x;   // 5,120,000
    int a = i >> 7, c = i & 127;
    int s = cidx[a];
    const __half* xh = reinterpret_cast<const __half*>(ws + O_X);
    float coef = ws[O_W + a] / ws[O_STAT + SWC + s];
    atomicAdd(&ws[O_CRYS + (size_t)s * 128 + c], coef * __half2float(xh[(size_t)i]));
}

__global__ __launch_bounds__(256) void k_head(const float* __restrict__ fc1W,
        const float* __restrict__ fc1b, const float* __restrict__ fc2W,
        const float* __restrict__ fc2b, const float* __restrict__ outW,
        const float* __restrict__ outb, const float* __restrict__ ws,
        float* __restrict__ out) {
    __shared__ float spx[128], h1[256], h2[256], rr[4];
    int b = blockIdx.x, t = threadIdx.x;
    if (t < 128) spx[t] = sp_f(ws[O_CRYS + (size_t)b * 128 + t]);
    __syncthreads();
    float acc = fc1b[t];
    for (int k = 0; k < 128; k++) acc += spx[k] * fc1W[k * 256 + t];
    h1[t] = sp_f(acc);
    __syncthreads();
    acc = fc2b[t];
    for (int k = 0; k < 256; k++) acc += h1[k] * fc2W[k * 256 + t];
    h2[t] = sp_f(acc);
    __syncthreads();
    float p = h2[t] * outW[t];
    for (int off = 32; off > 0; off >>= 1) p += __shfl_down(p, off, 64);
    if ((t & 63) == 0) rr[t >> 6] = p;
    __syncthreads();
    if (t == 0) out[b] = rr[0] + rr[1] + rr[2] + rr[3] + outb[0];
}

extern "C" void kernel_launch(void* const* d_in, const int* in_sizes, int n_in,
                              void* d_out, int out_size, void* d_ws, size_t ws_size,
                              hipStream_t stream) {
    const float* af   = (const float*)d_in[0];
    const float* nbr  = (const float*)d_in[1];
    const int*   eidx = (const int*)d_in[2];
    const int*   cidx = (const int*)d_in[3];
    const float* embW = (const float*)d_in[4];
    const float* embB = (const float*)d_in[5];
    const float* convW= (const float*)d_in[6];
    // d_in[7] = conv_b: cancels exactly in the weighted BN that follows the conv GEMM
    const float* bn1g = (const float*)d_in[8];
    const float* bn1b = (const float*)d_in[9];
    const float* bn2g = (const float*)d_in[10];
    const float* bn2b = (const float*)d_in[11];
    const float* fc1W = (const float*)d_in[12];
    const float* fc1b = (const float*)d_in[13];
    const float* fc2W = (const float*)d_in[14];
    const float* fc2b = (const float*)d_in[15];
    const float* outW = (const float*)d_in[16];
    const float* outb = (const float*)d_in[17];
    float* ws = (float*)d_ws;
    float* out = (float*)d_out;

    // zero: SWA/SWC region + crys
    hipMemsetAsync(ws + O_STAT + 1792, 0, (size_t)(2304 + 51200) * sizeof(float), stream);
    k_embed<<<1250, 128, 0, stream>>>(af, embW, embB, ws);
    k_pool1<<<157, 256, 0, stream>>>(cidx, ws);

    // CSR build (per call; eidx constant across convs)
    hipMemsetAsync(ws + O_DEG, 0, (size_t)40000 * sizeof(int), stream);
    k_hist<<<1563, 256, 0, stream>>>(eidx, ws);
    k_scan<<<1, 1024, 0, stream>>>(ws);
    hipMemsetAsync(ws + O_DEG, 0, (size_t)40000 * sizeof(int), stream);
    k_scatter<<<1563, 256, 0, stream>>>(eidx, ws);

    for (int i = 0; i < 3; i++) {
        hipMemsetAsync(ws + O_SUM, 0, (size_t)5120000 * sizeof(float), stream);
        hipMemsetAsync(ws + O_STAT, 0, (size_t)772 * sizeof(float), stream);
        const float* Wi = convW + (size_t)i * 297 * 256;
        k_wperm<<<256, 256, 0, stream>>>(Wi, ws);
        k_wh<<<64, 256, 0, stream>>>(Wi, ws);
        k_xcat<<<1250, 256, 0, stream>>>(ws);
        k_edge<0><<<6250, 256, 0, stream>>>(nbr, eidx, ws);
        k_fin1<<<1, 256, 0, stream>>>(bn1g + i * 256, bn1b + i * 256, ws);
        k_edge<1><<<6250, 256, 0, stream>>>(nbr, eidx, ws);
        k_stats2<<<256, 256, 0, stream>>>(ws);
        k_fin2<<<1, 128, 0, stream>>>(bn2g + i * 128, bn2b + i * 128, ws);
        k_updx<<<5000, 256, 0, stream>>>(ws);
    }
    k_pool2<<<20000, 256, 0, stream>>>(cidx, ws);
    k_head<<<400, 256, 0, stream>>>(fc1W, fc1b, fc2W, fc2b, outW, outb, ws, out);
}